// Round 4
// baseline (1558.532 us; speedup 1.0000x reference)
//
#include <hip/hip_runtime.h>
#include <math.h>

// Problem constants
#define BB 2
#define LL 1024
#define HIDD 1024
#define NH 4
#define DD 256
#define NCH 32
#define ROWS 2048
#define HROWS 8192

typedef long long i64;
typedef unsigned short u16t;
typedef unsigned int u32t;
typedef __attribute__((ext_vector_type(8))) short short8;
typedef __attribute__((ext_vector_type(4))) float f32x4;
#define MFMA_BF16(a, b, c) __builtin_amdgcn_mfma_f32_16x16x32_bf16(a, b, c, 0, 0, 0)

__device__ __forceinline__ float sigmoidf_(float x) { return 1.0f / (1.0f + expf(-x)); }

__device__ __forceinline__ u16t f2bf(float f) {
  u32t u = __float_as_uint(f);
  u = u + 0x7FFFu + ((u >> 16) & 1u);
  return (u16t)(u >> 16);
}
__device__ __forceinline__ u32t pk2(u16t a, u16t b) { return (u32t)a | ((u32t)b << 16); }

// ---------------- block reduction helper (blockDim == 256) ----------------
template<int N>
__device__ __forceinline__ void block_reduce_sum(float* v, float* scratch) {
  int lane = threadIdx.x & 63, wid = threadIdx.x >> 6;
#pragma unroll
  for (int i = 0; i < N; i++) {
    float x = v[i];
#pragma unroll
    for (int off = 1; off < 64; off <<= 1) x += __shfl_xor(x, off);
    if (lane == 0) scratch[wid * N + i] = x;
  }
  __syncthreads();
#pragma unroll
  for (int i = 0; i < N; i++)
    v[i] = scratch[i] + scratch[N + i] + scratch[2 * N + i] + scratch[3 * N + i];
  __syncthreads();
}

// ---------------- cast fp32 -> bf16 ----------------
__global__ __launch_bounds__(256) void castbf_kernel(
    const float* __restrict__ in, u16t* __restrict__ out, int n4) {
  int idx = blockIdx.x * 256 + threadIdx.x;
  if (idx >= n4) return;
  int e = idx * 4;
  float4 v = *(const float4*)(in + (i64)e);
  uint2 o;
  o.x = pk2(f2bf(v.x), f2bf(v.y));
  o.y = pk2(f2bf(v.z), f2bf(v.w));
  *(uint2*)(out + (i64)e) = o;
}

// ---------------- transpose + cast: in fp32 [K][N] -> out bf16 [N][K] ----------------
__global__ __launch_bounds__(256) void transcast_kernel(
    const float* __restrict__ in, int ldin, int col0,
    u16t* __restrict__ out, int ldout) {
  __shared__ float tile[32][33];
  int tx = threadIdx.x & 31, ty = threadIdx.x >> 5;
  int nb = blockIdx.x * 32, kb = blockIdx.y * 32;
#pragma unroll
  for (int r = 0; r < 4; r++)
    tile[ty + r * 8][tx] = in[(i64)(kb + ty + r * 8) * ldin + col0 + nb + tx];
  __syncthreads();
#pragma unroll
  for (int r = 0; r < 4; r++)
    out[(i64)(nb + ty + r * 8) * ldout + kb + tx] = f2bf(tile[tx][ty + r * 8]);
}

// ---------------- bf16 MFMA GEMM: A[M][K] bf16, B[N][K] bf16, C[M][N] fp32 ----------------
__global__ __launch_bounds__(256) void gemm_bt_kernel(
    const u16t* __restrict__ A, const u16t* __restrict__ B,
    float* __restrict__ C, int K, int ldc) {
  __shared__ u16t As[128 * 40];
  __shared__ u16t Bs[128 * 40];
  int t = threadIdx.x;
  int n0 = blockIdx.x * 128, m0 = blockIdx.y * 128;
  int w = t >> 6, lane = t & 63;
  int l15 = lane & 15, quad = lane >> 4;
  int wm = (w & 1) * 64, wn = (w >> 1) * 64;
  f32x4 acc[4][4] = {};
  int srow = t >> 1, shalf = (t & 1) * 16;
  const u16t* Ag = A + (i64)(m0 + srow) * K + shalf;
  const u16t* Bg = B + (i64)(n0 + srow) * K + shalf;
  for (int k0 = 0; k0 < K; k0 += 32) {
    *(uint4*)&As[srow * 40 + shalf] = *(const uint4*)(Ag + k0);
    *(uint4*)&As[srow * 40 + shalf + 8] = *(const uint4*)(Ag + k0 + 8);
    *(uint4*)&Bs[srow * 40 + shalf] = *(const uint4*)(Bg + k0);
    *(uint4*)&Bs[srow * 40 + shalf + 8] = *(const uint4*)(Bg + k0 + 8);
    __syncthreads();
    short8 a[4], b[4];
#pragma unroll
    for (int mt = 0; mt < 4; mt++)
      a[mt] = *(const short8*)&As[(wm + mt * 16 + l15) * 40 + quad * 8];
#pragma unroll
    for (int nt = 0; nt < 4; nt++)
      b[nt] = *(const short8*)&Bs[(wn + nt * 16 + l15) * 40 + quad * 8];
#pragma unroll
    for (int mt = 0; mt < 4; mt++)
#pragma unroll
      for (int nt = 0; nt < 4; nt++)
        acc[mt][nt] = MFMA_BF16(a[mt], b[nt], acc[mt][nt]);
    __syncthreads();
  }
#pragma unroll
  for (int mt = 0; mt < 4; mt++) {
    int r0 = m0 + wm + mt * 16 + quad * 4;
#pragma unroll
    for (int nt = 0; nt < 4; nt++) {
      int cc = n0 + wn + nt * 16 + l15;
#pragma unroll
      for (int rg = 0; rg < 4; rg++)
        C[(i64)(r0 + rg) * ldc + cc] = acc[mt][nt][rg];
    }
  }
}

// ---------------- fused causal depthwise conv (K=4) + silu for q,k,v ----------------
__global__ __launch_bounds__(256) void conv_silu3_kernel(
    const float* __restrict__ pre, const float* __restrict__ qw,
    const float* __restrict__ kw, const float* __restrict__ vw,
    float* __restrict__ qo, float* __restrict__ ko, float* __restrict__ vo,
    u16t* __restrict__ brcat) {
  int seg = blockIdx.x >> 13;
  int idx = (blockIdx.x & 8191) * 256 + threadIdx.x;
  int c = idx & 1023, row = idx >> 10, l = row & 1023;
  const float* w = seg == 0 ? qw : seg == 1 ? kw : vw;
  float* out = seg == 0 ? qo : seg == 1 ? ko : vo;
  float4 wv = *(const float4*)(w + c * 4);
  const float* base = pre + (i64)row * 3072 + (seg << 10) + c;
  float acc = wv.w * base[0];
  if (l >= 1) acc += wv.z * base[-3072];
  if (l >= 2) acc += wv.y * base[-2 * 3072];
  if (l >= 3) acc += wv.x * base[-3 * 3072];
  float r = acc * sigmoidf_(acc);
  out[(i64)row * 1024 + c] = r;
  if (seg == 2)
    brcat[((i64)row * 4 + (c >> 8)) * 1024 + 768 + (c & 255)] = f2bf(r);
}

// ---------------- beta = sigmoid(x @ Wb) ----------------
__global__ __launch_bounds__(256) void beta_kernel(
    const float* __restrict__ x, const float* __restrict__ Wb, float* __restrict__ beta) {
  int row = blockIdx.x, t = threadIdx.x;
  __shared__ float sc[16];
  float a[4] = {0, 0, 0, 0};
  for (int c = t; c < 1024; c += 256) {
    float xv = x[(i64)row * 1024 + c];
    float4 wv = *(const float4*)(Wb + c * 4);
    a[0] += xv * wv.x; a[1] += xv * wv.y; a[2] += xv * wv.z; a[3] += xv * wv.w;
  }
  block_reduce_sum<4>(a, sc);
  if (t == 0) {
#pragma unroll
    for (int g = 0; g < 4; g++) beta[row * 4 + g] = sigmoidf_(a[g]);
  }
}

// ---------------- l2norm(q,k), v*beta, kn*beta; qn also emitted bf16 in delta layout ----------------
__global__ __launch_bounds__(256) void preprocess_kernel(
    const float* __restrict__ q, const float* __restrict__ k, const float* __restrict__ v,
    const float* __restrict__ beta, float* __restrict__ qn, float* __restrict__ kn,
    float* __restrict__ vb, float* __restrict__ kb, u16t* __restrict__ qnbf) {
  int row = blockIdx.x, t = threadIdx.x;   // row = (b*1024+l)*4+h
  __shared__ float sc[8];
  i64 base = (i64)row * 256 + t;
  float qv = q[base], kv = k[base], vv = v[base];
  float vals[2] = {qv * qv, kv * kv};
  block_reduce_sum<2>(vals, sc);
  float qi = rsqrtf(vals[0] + 1e-6f), ki = rsqrtf(vals[1] + 1e-6f);
  float bet = beta[row];
  float qnv = qv * qi, knv = kv * ki;
  qn[base] = qnv;
  kn[base] = knv;
  vb[base] = vv * bet;
  kb[base] = knv * bet;
  int b = row >> 12, l = (row >> 2) & 1023, h = row & 3;
  qnbf[((i64)(b * 4 + h) * 1024 + l) * 256 + t] = f2bf(qnv);
}

// ---------------- phase A: per-chunk UT-transform; emits u fp32, w bf16(neg), attn bf16, knT bf16 ----------------
__global__ __launch_bounds__(256) void phaseA_kernel(
    const float* __restrict__ qn, const float* __restrict__ kn,
    const float* __restrict__ vb, const float* __restrict__ kb,
    float* __restrict__ u_g, u16t* __restrict__ w_bf, u16t* __restrict__ attn_bf,
    u16t* __restrict__ knT) {
  __shared__ float KN[32][260];
  __shared__ float Ms[32][32];
  int blk = blockIdx.x, t = threadIdx.x;
  int i = blk & 31, bh = blk >> 5;
  int rbase = ((bh >> 2) * LL + i * 32) * NH + (bh & 3);
  i64 bhn = blk;   // = bh*32 + i
#pragma unroll
  for (int ii = 0; ii < 8; ii++) {
    int fid = t + ii * 256;
    int c = fid >> 6, dq = (fid & 63) << 2;
    *(float4*)&KN[c][dq] = *(const float4*)(kn + (i64)(rbase + c * NH) * 256 + dq);
  }
  __syncthreads();
  int c = t >> 3, e0 = (t & 7) * 4;
  const float* kbp = kb + (i64)(rbase + c * NH) * 256;
  const float* qp = qn + (i64)(rbase + c * NH) * 256;
  float am[4] = {0, 0, 0, 0}, aa[4] = {0, 0, 0, 0};
  for (int d = 0; d < 256; d += 4) {
    float4 kv = *(const float4*)(kbp + d);
    float4 qv = *(const float4*)(qp + d);
#pragma unroll
    for (int z = 0; z < 4; z++) {
      float4 nv = *(const float4*)&KN[e0 + z][d];
      am[z] += kv.x * nv.x + kv.y * nv.y + kv.z * nv.z + kv.w * nv.w;
      aa[z] += qv.x * nv.x + qv.y * nv.y + qv.z * nv.z + qv.w * nv.w;
    }
  }
  {
    uint2 o;
    u16t a0 = (e0 + 0 <= c) ? f2bf(aa[0]) : 0;
    u16t a1 = (e0 + 1 <= c) ? f2bf(aa[1]) : 0;
    u16t a2 = (e0 + 2 <= c) ? f2bf(aa[2]) : 0;
    u16t a3 = (e0 + 3 <= c) ? f2bf(aa[3]) : 0;
    o.x = pk2(a0, a1); o.y = pk2(a2, a3);
    *(uint2*)(attn_bf + bhn * 1024 + c * 32 + e0) = o;
  }
#pragma unroll
  for (int z = 0; z < 4; z++) {
    int e = e0 + z;
    Ms[c][e] = (e < c) ? am[z] : 0.0f;
  }
  __syncthreads();
  // forward substitution, thread = column d
  float uc[32], wc[32];
#pragma unroll
  for (int cc = 0; cc < 32; cc++) {
    float uval = vb[(i64)(rbase + cc * NH) * 256 + t];
    float wval = kb[(i64)(rbase + cc * NH) * 256 + t];
#pragma unroll
    for (int c2 = 0; c2 < cc; c2++) {
      float m = Ms[cc][c2];
      uval -= m * uc[c2];
      wval -= m * wc[c2];
    }
    uc[cc] = uval; wc[cc] = wval;
    u_g[(bhn * 32 + cc) * 256 + t] = uval;
    w_bf[(bhn * 32 + cc) * 256 + t] = f2bf(-wval);
  }
  // emit knT [bhn][d][c] bf16 from the staged KN tile
  int d = t;
  u16t o[32];
#pragma unroll
  for (int cc = 0; cc < 32; cc++) o[cc] = f2bf(KN[cc][d]);
#pragma unroll
  for (int z = 0; z < 4; z++) {
    uint4 vv;
    vv.x = pk2(o[z * 8 + 0], o[z * 8 + 1]);
    vv.y = pk2(o[z * 8 + 2], o[z * 8 + 3]);
    vv.z = pk2(o[z * 8 + 4], o[z * 8 + 5]);
    vv.w = pk2(o[z * 8 + 6], o[z * 8 + 7]);
    *(uint4*)(knT + (bhn * 256 + d) * 32 + z * 8) = vv;
  }
}

// ---------------- fused delta scan: u' + o + S-update in one sequential pass ----------------
// grid 128 = bh(8) x jb(16). Waves 0-1: u' = u - w@S. Waves 2-3: o = q@S + attn@u'.
// All waves: S += knT @ u' (S in fp32 accumulators, bf16 snapshot in LDS).
__global__ __launch_bounds__(256) void delta_scan_kernel(
    const u16t* __restrict__ wbf, const u16t* __restrict__ knT,
    const float* __restrict__ u_g, const u16t* __restrict__ qnbf,
    const u16t* __restrict__ attnbf,
    float* __restrict__ dlt, u16t* __restrict__ brcat) {
  __shared__ u16t Sbf[16 * 272];   // [j][d] bf16 snapshot
  __shared__ u16t Ubf[16 * 40];    // [j][c] u' chunk
  int t = threadIdx.x, w = t >> 6, lane = t & 63;
  int l15 = lane & 15, quad = lane >> 4;
  int bh = blockIdx.x >> 4, jb = blockIdx.x & 15, j0 = jb * 16;
  int b_ = bh >> 2, h_ = bh & 3;
  bool isU = (w < 2);
  int wc = isU ? w : (w - 2);
  for (int idx = t; idx < 16 * 272; idx += 256) Sbf[idx] = 0;
  f32x4 accS[4] = {};
  __syncthreads();

  short8 m8[2][8]; f32x4 uc4[2]; short8 af[2]; short8 kf[2][4];
  auto load_chunk = [&](int i, int buf) {
    i64 bhn = (i64)bh * 32 + i;
    const u16t* mbase = isU
        ? wbf + (bhn * 32 + wc * 16 + l15) * 256 + quad * 8
        : qnbf + ((i64)bh * 1024 + i * 32 + wc * 16 + l15) * 256 + quad * 8;
#pragma unroll
    for (int kd = 0; kd < 8; kd++) m8[buf][kd] = *(const short8*)(mbase + kd * 32);
    if (isU) {
      int cm = wc * 16 + quad * 4;
#pragma unroll
      for (int r = 0; r < 4; r++)
        uc4[buf][r] = u_g[(bhn * 32 + cm + r) * 256 + j0 + l15];
    } else {
      af[buf] = *(const short8*)(attnbf + bhn * 1024 + (wc * 16 + l15) * 32 + quad * 8);
    }
#pragma unroll
    for (int dt = 0; dt < 4; dt++)
      kf[buf][dt] = *(const short8*)(knT + (bhn * 256 + w * 64 + dt * 16 + l15) * 32 + quad * 8);
  };

  load_chunk(0, 0);
  for (int i = 0; i < 32; i++) {
    int cur = i & 1, nxt = cur ^ 1;
    if (i < 31) load_chunk(i + 1, nxt);
    // phase 1: u' (waves 0-1) and q@S (waves 2-3), both read Sbf
    f32x4 zero = {};
    f32x4 cacc = isU ? uc4[cur] : zero;
#pragma unroll
    for (int kd = 0; kd < 8; kd++) {
      short8 sf = *(const short8*)&Sbf[l15 * 272 + kd * 32 + quad * 8];
      cacc = MFMA_BF16(m8[cur][kd], sf, cacc);
    }
    if (isU) {
      int cm = wc * 16 + quad * 4;
      uint2 o;
      o.x = pk2(f2bf(cacc[0]), f2bf(cacc[1]));
      o.y = pk2(f2bf(cacc[2]), f2bf(cacc[3]));
      *(uint2*)&Ubf[l15 * 40 + cm] = o;
    }
    __syncthreads();
    short8 bu = *(const short8*)&Ubf[l15 * 40 + quad * 8];
    if (!isU) {
      cacc = MFMA_BF16(af[cur], bu, cacc);
#pragma unroll
      for (int rg = 0; rg < 4; rg++) {
        int l = i * 32 + wc * 16 + quad * 4 + rg;
        i64 row = ((i64)b_ * 1024 + l) * 4 + h_;
        dlt[row * 256 + j0 + l15] = cacc[rg];
        brcat[row * 1024 + 512 + j0 + l15] = f2bf(cacc[rg]);
      }
    }
    // S update: S[d slice][j] += knT @ u'
#pragma unroll
    for (int dt = 0; dt < 4; dt++) accS[dt] = MFMA_BF16(kf[cur][dt], bu, accS[dt]);
#pragma unroll
    for (int dt = 0; dt < 4; dt++) {
      uint2 o;
      o.x = pk2(f2bf(accS[dt][0]), f2bf(accS[dt][1]));
      o.y = pk2(f2bf(accS[dt][2]), f2bf(accS[dt][3]));
      *(uint2*)&Sbf[l15 * 272 + w * 64 + dt * 16 + quad * 4] = o;
    }
    __syncthreads();
  }
}

// ---------------- per-head depthwise causal FIR (+ bf16 branch copy) ----------------
__global__ __launch_bounds__(256) void fir_kernel(
    const float* __restrict__ v, const float* __restrict__ f, float* __restrict__ out,
    u16t* __restrict__ brcat, int col0, int K) {
  __shared__ float fb[256 * 31];
  int row = blockIdx.x, t = threadIdx.x;
  int h = row & 3, l = (row >> 2) & (LL - 1);
  for (int idx = t; idx < 256 * K; idx += 256) fb[idx] = f[h * 256 * K + idx];
  __syncthreads();
  float acc = 0.0f;
  int jmin = (K - 1) - l; if (jmin < 0) jmin = 0;
  for (int jj = jmin; jj < K; jj++) {
    int dl = jj - (K - 1);
    acc += fb[t * K + jj] * v[(i64)(row + dl * NH) * 256 + t];
  }
  out[(i64)row * 256 + t] = acc;
  brcat[(i64)row * 1024 + col0 + t] = f2bf(acc);
}

// ---------------- per-(row,branch) stats ----------------
__global__ __launch_bounds__(256) void stats_kernel(
    const float* __restrict__ fs, const float* __restrict__ fl,
    const float* __restrict__ dlt, const float* __restrict__ v, float* __restrict__ stat) {
  int row = blockIdx.x, t = threadIdx.x;
  __shared__ float sc[8];
  __shared__ float scm[4];
  const float* brs[4] = {fs, fl, dlt, v};
#pragma unroll
  for (int p = 0; p < 4; p++) {
    float x = brs[p][(i64)row * 256 + t];
    float vals[2] = {x, x * x};
    block_reduce_sum<2>(vals, sc);
    float m = x;
#pragma unroll
    for (int off = 1; off < 64; off <<= 1) m = fmaxf(m, __shfl_xor(m, off));
    int lane = t & 63, wid = t >> 6;
    if (lane == 0) scm[wid] = m;
    __syncthreads();
    if (t == 0) {
      float mx = fmaxf(fmaxf(scm[0], scm[1]), fmaxf(scm[2], scm[3]));
      stat[row * 12 + p * 3 + 0] = vals[0] * (1.0f / 256.0f);
      stat[row * 12 + p * 3 + 1] = sqrtf(fmaxf(vals[1] * (1.0f / 256.0f), 1e-8f));
      stat[row * 12 + p * 3 + 2] = mx;
    }
    __syncthreads();
  }
}

// ---------------- W1 stat-block column sums (96 blocks, atomic accumulate) ----------------
__global__ __launch_bounds__(256) void wsum_kernel(const float* __restrict__ W1, float* __restrict__ Wsum) {
  int blk = blockIdx.x;        // 96 = 12 stats * 8 row-chunks
  int s = blk >> 3, rc = blk & 7;
  int t = threadIdx.x;
  const float* p = W1 + (i64)(1024 + s * 256 + rc * 32) * 512;
  float a0 = 0.0f, a1 = 0.0f;
  for (int r = 0; r < 32; r++) {
    a0 += p[(i64)r * 512 + t];
    a1 += p[(i64)r * 512 + t + 256];
  }
  atomicAdd(&Wsum[s * 512 + t], a0);
  atomicAdd(&Wsum[s * 512 + t + 256], a1);
}

// ---------------- gate MLP tail ----------------
__global__ __launch_bounds__(256) void gate_kernel(
    const float* __restrict__ hbase, const float* __restrict__ brW,
    const float* __restrict__ stat, const float* __restrict__ wsum,
    const float* __restrict__ gb1, const float* __restrict__ gW2,
    const float* __restrict__ gb2, const float* __restrict__ temp,
    const float* __restrict__ epsf, float* __restrict__ gw) {
  int row = blockIdx.x, t = threadIdx.x;
  int bl = row >> 2, h = row & 3;
  __shared__ float sc[16];
  float st[12];
#pragma unroll
  for (int s = 0; s < 12; s++) st[s] = stat[row * 12 + s];
  float lg[4] = {0, 0, 0, 0};
  for (int o = t; o < 512; o += 256) {
    float hm = hbase[(i64)bl * 512 + o] + brW[(i64)row * 512 + o] + gb1[o];
#pragma unroll
    for (int s = 0; s < 12; s++) hm += st[s] * wsum[s * 512 + o];
    float ge = 0.5f * hm * (1.0f + erff(hm * 0.70710678118654752f));
    float4 w2 = *(const float4*)(gW2 + o * 4);
    lg[0] += ge * w2.x; lg[1] += ge * w2.y; lg[2] += ge * w2.z; lg[3] += ge * w2.w;
  }
  block_reduce_sum<4>(lg, sc);
  if (t == 0) {
    float tt = fminf(fmaxf(temp[h], 0.2f), 10.0f);
    float l0 = (lg[0] + gb2[0]) / tt;
    float l1 = (lg[1] + gb2[1]) / tt;
    float l2 = (lg[2] + gb2[2]) / tt;
    float l3 = (lg[3] + gb2[3]) / tt;
    float m = fmaxf(fmaxf(l0, l1), fmaxf(l2, l3));
    float e0 = expf(l0 - m), e1 = expf(l1 - m), e2 = expf(l2 - m), e3 = expf(l3 - m);
    float ssum = e0 + e1 + e2 + e3;
    float w0 = e0 / ssum, w1 = e1 / ssum, w2 = e2 / ssum, w3 = e3 / ssum;
    w0 = fmaxf(w0, fminf(fmaxf(epsf[h * 4 + 0], 1e-7f), 0.1f));
    w1 = fmaxf(w1, fminf(fmaxf(epsf[h * 4 + 1], 1e-7f), 0.1f));
    w2 = fmaxf(w2, fminf(fmaxf(epsf[h * 4 + 2], 1e-7f), 0.1f));
    w3 = fmaxf(w3, fminf(fmaxf(epsf[h * 4 + 3], 1e-7f), 0.1f));
    float s2 = w0 + w1 + w2 + w3;
    gw[row * 4 + 0] = w0 / s2;
    gw[row * 4 + 1] = w1 / s2;
    gw[row * 4 + 2] = w2 / s2;
    gw[row * 4 + 3] = w3 / s2;
  }
}

// ---------------- weighted mix + RMS norm -> bf16 [2048][1024] ----------------
__global__ __launch_bounds__(256) void mix_kernel(
    const float* __restrict__ fs, const float* __restrict__ fl,
    const float* __restrict__ dlt, const float* __restrict__ v,
    const float* __restrict__ gw, const float* __restrict__ onw, u16t* __restrict__ out) {
  int row = blockIdx.x, t = threadIdx.x;
  __shared__ float sc[4];
  i64 base = (i64)row * 256 + t;
  float4 wv = *(const float4*)(gw + row * 4);
  float o = wv.x * fs[base] + wv.y * fl[base] + wv.z * dlt[base] + wv.w * v[base];
  float vals[1] = {o * o};
  block_reduce_sum<1>(vals, sc);
  float scale = rsqrtf(vals[0] * (1.0f / 256.0f) + 1e-5f);
  out[(i64)(row >> 2) * 1024 + (row & 3) * 256 + t] = f2bf(o * scale * onw[t]);
}

extern "C" void kernel_launch(void* const* d_in, const int* in_sizes, int n_in,
                              void* d_out, int out_size, void* d_ws, size_t ws_size,
                              hipStream_t stream) {
  (void)in_sizes; (void)n_in; (void)out_size; (void)ws_size;
  const float* x    = (const float*)d_in[0];
  const float* Wq   = (const float*)d_in[1];
  const float* Wk   = (const float*)d_in[2];
  const float* Wv   = (const float*)d_in[3];
  const float* Wb   = (const float*)d_in[4];
  const float* qcw  = (const float*)d_in[5];
  const float* kcw  = (const float*)d_in[6];
  const float* vcw  = (const float*)d_in[7];
  const float* gW1  = (const float*)d_in[8];
  const float* gb1  = (const float*)d_in[9];
  const float* gW2  = (const float*)d_in[10];
  const float* gb2  = (const float*)d_in[11];
  const float* temp = (const float*)d_in[12];
  const float* epsf = (const float*)d_in[13];
  const float* onw  = (const float*)d_in[14];
  const float* Wo   = (const float*)d_in[15];
  const float* firs = (const float*)d_in[16];
  const float* firl = (const float*)d_in[17];
  float* out = (float*)d_out;

  float* ws = (float*)d_ws;
  // ---- workspace map (float offsets) ----
  // [0, 6291456): qkv_pre (steps 2-3) -> branchW@0 + hbase@4194304 (steps 12+)
  float* qkv_pre  = ws + 0;                       // 2048*3072 fp32
  float* branchW  = ws + 0;                       // 8192*512 fp32
  float* hbase    = ws + 4194304;                 // 2048*512 fp32
  u16t*  brcat    = (u16t*)(ws + 6291456);        // 8192*1024 bf16 (own region)
  float* qbuf     = ws + 10485760; float* qn = qbuf;
  float* kbuf     = ws + 12582912; float* kn = kbuf;
  float* vbuf     = ws + 14680064;
  float* vb       = ws + 16777216;                // dead after phaseA
  u16t*  omix_bf  = (u16t*)(ws + 16777216);       // 2048*1024 bf16 (step 16+)
  u16t*  W1hT     = (u16t*)(ws + 17825792);       // 512*1024 bf16 (step 12+)
  u16t*  W1bT     = (u16t*)(ws + 18087936);       // 512*1024 bf16
  u16t*  WoT      = (u16t*)(ws + 18350080);       // 1024*1024 bf16
  float* kb       = ws + 18874368;                // dead after phaseA
  float* dlt      = ws + 18874368;                // scan output (step 8+)
  float* u_g      = ws + 20971520;                // phaseA -> scan
  u16t*  w_bf     = (u16t*)(ws + 23068672);       // negated w bf16
  u16t*  qn_bf    = (u16t*)(ws + 24117248);
  u16t*  knT      = (u16t*)(ws + 25165824);
  u16t*  attn_bf  = (u16t*)(ws + 26214400);
  float* fs       = ws + 26345472;
  float* fl       = ws + 28442624;
  u16t*  xbf      = (u16t*)(ws + 30539776);
  u16t*  WqkvT    = (u16t*)(ws + 31588352);       // 3072*1024 bf16
  float* betab    = ws + 33161216;
  float* stat     = ws + 33169408;
  float* wsum     = ws + 33267712;                // 12*512 fp32
  float* gw       = ws + 33273856;

  // 1) casts + QKV weight transposes
  castbf_kernel<<<2048, 256, 0, stream>>>(x, xbf, 524288);
  transcast_kernel<<<dim3(32, 32), 256, 0, stream>>>(Wq, 1024, 0, WqkvT, 1024);
  transcast_kernel<<<dim3(32, 32), 256, 0, stream>>>(Wk, 1024, 0, WqkvT + 1024 * 1024, 1024);
  transcast_kernel<<<dim3(32, 32), 256, 0, stream>>>(Wv, 1024, 0, WqkvT + 2048 * 1024, 1024);
  // 2) QKV GEMM
  gemm_bt_kernel<<<dim3(24, 16), 256, 0, stream>>>(xbf, WqkvT, qkv_pre, 1024, 3072);
  // 3) fused conv+silu (v also -> brcat col 768)
  conv_silu3_kernel<<<24576, 256, 0, stream>>>(qkv_pre, qcw, kcw, vcw, qbuf, kbuf, vbuf, brcat);
  // 4) beta + preprocess (emits qn_bf)
  beta_kernel<<<2048, 256, 0, stream>>>(x, Wb, betab);
  preprocess_kernel<<<8192, 256, 0, stream>>>(qbuf, kbuf, vbuf, betab, qn, kn, vb, kb, qn_bf);
  // 5) phase A (fp32 substitution; emits u fp32, w/attn/knT bf16)
  phaseA_kernel<<<256, 256, 0, stream>>>(qn, kn, vb, kb, u_g, w_bf, attn_bf, knT);
  // 6) fused delta scan (emits dlt fp32 + brcat col 512)
  delta_scan_kernel<<<128, 256, 0, stream>>>(w_bf, knT, u_g, qn_bf, attn_bf, dlt, brcat);
  // 7) FIR branches (emit fp32 + brcat cols 0 / 256)
  fir_kernel<<<8192, 256, 0, stream>>>(vbuf, firs, fs, brcat, 0, 3);
  fir_kernel<<<8192, 256, 0, stream>>>(vbuf, firl, fl, brcat, 256, 31);
  // 8) stats + wsum
  stats_kernel<<<8192, 256, 0, stream>>>(fs, fl, dlt, vbuf, stat);
  hipMemsetAsync(wsum, 0, 12 * 512 * sizeof(float), stream);
  wsum_kernel<<<96, 256, 0, stream>>>(gW1, wsum);
  // 9) gate GEMMs
  transcast_kernel<<<dim3(16, 32), 256, 0, stream>>>(gW1, 512, 0, W1hT, 1024);
  transcast_kernel<<<dim3(16, 32), 256, 0, stream>>>(gW1 + (i64)4096 * 512, 512, 0, W1bT, 1024);
  gemm_bt_kernel<<<dim3(4, 16), 256, 0, stream>>>(xbf, W1hT, hbase, 1024, 512);
  gemm_bt_kernel<<<dim3(4, 64), 256, 0, stream>>>(brcat, W1bT, branchW, 1024, 512);
  // 10) gate tail + mix (mix emits bf16 directly)
  gate_kernel<<<8192, 256, 0, stream>>>(hbase, branchW, stat, wsum, gb1, gW2, gb2, temp, epsf, gw);
  mix_kernel<<<8192, 256, 0, stream>>>(fs, fl, dlt, vbuf, gw, onw, omix_bf);
  // 11) final projection
  transcast_kernel<<<dim3(32, 32), 256, 0, stream>>>(Wo, 1024, 0, WoT, 1024);
  gemm_bt_kernel<<<dim3(8, 16), 256, 0, stream>>>(omix_bf, WoT, out, 1024, 1024);
}

// Round 5
// 473.735 us; speedup vs baseline: 3.2899x; 3.2899x over previous
//
#include <hip/hip_runtime.h>
#include <math.h>

// Problem constants
#define BB 2
#define LL 1024
#define HIDD 1024
#define NH 4
#define DD 256
#define NCH 32
#define ROWS 2048
#define HROWS 8192

typedef long long i64;
typedef unsigned short u16t;
typedef unsigned int u32t;
typedef __attribute__((ext_vector_type(8))) short short8;
typedef __attribute__((ext_vector_type(4))) float f32x4;
#define MFMA_BF16(a, b, c) __builtin_amdgcn_mfma_f32_16x16x32_bf16(a, b, c, 0, 0, 0)

__device__ __forceinline__ float sigmoidf_(float x) { return 1.0f / (1.0f + expf(-x)); }

__device__ __forceinline__ u16t f2bf(float f) {
  u32t u = __float_as_uint(f);
  u = u + 0x7FFFu + ((u >> 16) & 1u);
  return (u16t)(u >> 16);
}
__device__ __forceinline__ u32t pk2(u16t a, u16t b) { return (u32t)a | ((u32t)b << 16); }

// ---------------- block reduction helper (blockDim == 256) ----------------
template<int N>
__device__ __forceinline__ void block_reduce_sum(float* v, float* scratch) {
  int lane = threadIdx.x & 63, wid = threadIdx.x >> 6;
#pragma unroll
  for (int i = 0; i < N; i++) {
    float x = v[i];
#pragma unroll
    for (int off = 1; off < 64; off <<= 1) x += __shfl_xor(x, off);
    if (lane == 0) scratch[wid * N + i] = x;
  }
  __syncthreads();
#pragma unroll
  for (int i = 0; i < N; i++)
    v[i] = scratch[i] + scratch[N + i] + scratch[2 * N + i] + scratch[3 * N + i];
  __syncthreads();
}

// ---------------- cast fp32 -> bf16 ----------------
__global__ __launch_bounds__(256) void castbf_kernel(
    const float* __restrict__ in, u16t* __restrict__ out, int n4) {
  int idx = blockIdx.x * 256 + threadIdx.x;
  if (idx >= n4) return;
  int e = idx * 4;
  float4 v = *(const float4*)(in + (i64)e);
  uint2 o;
  o.x = pk2(f2bf(v.x), f2bf(v.y));
  o.y = pk2(f2bf(v.z), f2bf(v.w));
  *(uint2*)(out + (i64)e) = o;
}

// ---------------- transpose + cast: in fp32 [K][N] -> out bf16 [N][K] ----------------
__global__ __launch_bounds__(256) void transcast_kernel(
    const float* __restrict__ in, int ldin, int col0,
    u16t* __restrict__ out, int ldout) {
  __shared__ float tile[32][33];
  int tx = threadIdx.x & 31, ty = threadIdx.x >> 5;
  int nb = blockIdx.x * 32, kb = blockIdx.y * 32;
#pragma unroll
  for (int r = 0; r < 4; r++)
    tile[ty + r * 8][tx] = in[(i64)(kb + ty + r * 8) * ldin + col0 + nb + tx];
  __syncthreads();
#pragma unroll
  for (int r = 0; r < 4; r++)
    out[(i64)(nb + ty + r * 8) * ldout + kb + tx] = f2bf(tile[tx][ty + r * 8]);
}

// ---------------- bf16 MFMA GEMM: A[M][K] bf16, B[N][K] bf16, C[M][N] fp32 ----------------
__global__ __launch_bounds__(256) void gemm_bt_kernel(
    const u16t* __restrict__ A, const u16t* __restrict__ B,
    float* __restrict__ C, int K, int ldc) {
  __shared__ u16t As[128 * 40];
  __shared__ u16t Bs[128 * 40];
  int t = threadIdx.x;
  int n0 = blockIdx.x * 128, m0 = blockIdx.y * 128;
  int w = t >> 6, lane = t & 63;
  int l15 = lane & 15, quad = lane >> 4;
  int wm = (w & 1) * 64, wn = (w >> 1) * 64;
  f32x4 acc[4][4] = {};
  int srow = t >> 1, shalf = (t & 1) * 16;
  const u16t* Ag = A + (i64)(m0 + srow) * K + shalf;
  const u16t* Bg = B + (i64)(n0 + srow) * K + shalf;
  for (int k0 = 0; k0 < K; k0 += 32) {
    *(uint4*)&As[srow * 40 + shalf] = *(const uint4*)(Ag + k0);
    *(uint4*)&As[srow * 40 + shalf + 8] = *(const uint4*)(Ag + k0 + 8);
    *(uint4*)&Bs[srow * 40 + shalf] = *(const uint4*)(Bg + k0);
    *(uint4*)&Bs[srow * 40 + shalf + 8] = *(const uint4*)(Bg + k0 + 8);
    __syncthreads();
    short8 a[4], b[4];
#pragma unroll
    for (int mt = 0; mt < 4; mt++)
      a[mt] = *(const short8*)&As[(wm + mt * 16 + l15) * 40 + quad * 8];
#pragma unroll
    for (int nt = 0; nt < 4; nt++)
      b[nt] = *(const short8*)&Bs[(wn + nt * 16 + l15) * 40 + quad * 8];
#pragma unroll
    for (int mt = 0; mt < 4; mt++)
#pragma unroll
      for (int nt = 0; nt < 4; nt++)
        acc[mt][nt] = MFMA_BF16(a[mt], b[nt], acc[mt][nt]);
    __syncthreads();
  }
#pragma unroll
  for (int mt = 0; mt < 4; mt++) {
    int r0 = m0 + wm + mt * 16 + quad * 4;
#pragma unroll
    for (int nt = 0; nt < 4; nt++) {
      int cc = n0 + wn + nt * 16 + l15;
#pragma unroll
      for (int rg = 0; rg < 4; rg++)
        C[(i64)(r0 + rg) * ldc + cc] = acc[mt][nt][rg];
    }
  }
}

// ---------------- fused causal depthwise conv (K=4) + silu for q,k,v ----------------
__global__ __launch_bounds__(256) void conv_silu3_kernel(
    const float* __restrict__ pre, const float* __restrict__ qw,
    const float* __restrict__ kw, const float* __restrict__ vw,
    float* __restrict__ qo, float* __restrict__ ko, float* __restrict__ vo,
    u16t* __restrict__ brcat) {
  int seg = blockIdx.x >> 13;
  int idx = (blockIdx.x & 8191) * 256 + threadIdx.x;
  int c = idx & 1023, row = idx >> 10, l = row & 1023;
  const float* w = seg == 0 ? qw : seg == 1 ? kw : vw;
  float* out = seg == 0 ? qo : seg == 1 ? ko : vo;
  float4 wv = *(const float4*)(w + c * 4);
  const float* base = pre + (i64)row * 3072 + (seg << 10) + c;
  float acc = wv.w * base[0];
  if (l >= 1) acc += wv.z * base[-3072];
  if (l >= 2) acc += wv.y * base[-2 * 3072];
  if (l >= 3) acc += wv.x * base[-3 * 3072];
  float r = acc * sigmoidf_(acc);
  out[(i64)row * 1024 + c] = r;
  if (seg == 2)
    brcat[((i64)row * 4 + (c >> 8)) * 1024 + 768 + (c & 255)] = f2bf(r);
}

// ---------------- beta = sigmoid(x @ Wb) ----------------
__global__ __launch_bounds__(256) void beta_kernel(
    const float* __restrict__ x, const float* __restrict__ Wb, float* __restrict__ beta) {
  int row = blockIdx.x, t = threadIdx.x;
  __shared__ float sc[16];
  float a[4] = {0, 0, 0, 0};
  for (int c = t; c < 1024; c += 256) {
    float xv = x[(i64)row * 1024 + c];
    float4 wv = *(const float4*)(Wb + c * 4);
    a[0] += xv * wv.x; a[1] += xv * wv.y; a[2] += xv * wv.z; a[3] += xv * wv.w;
  }
  block_reduce_sum<4>(a, sc);
  if (t == 0) {
#pragma unroll
    for (int g = 0; g < 4; g++) beta[row * 4 + g] = sigmoidf_(a[g]);
  }
}

// ---------------- l2norm(q,k), v*beta, kn*beta; qn also emitted bf16 in delta layout ----------------
__global__ __launch_bounds__(256) void preprocess_kernel(
    const float* __restrict__ q, const float* __restrict__ k, const float* __restrict__ v,
    const float* __restrict__ beta, float* __restrict__ qn, float* __restrict__ kn,
    float* __restrict__ vb, float* __restrict__ kb, u16t* __restrict__ qnbf) {
  int row = blockIdx.x, t = threadIdx.x;   // row = (b*1024+l)*4+h
  __shared__ float sc[8];
  i64 base = (i64)row * 256 + t;
  float qv = q[base], kv = k[base], vv = v[base];
  float vals[2] = {qv * qv, kv * kv};
  block_reduce_sum<2>(vals, sc);
  float qi = rsqrtf(vals[0] + 1e-6f), ki = rsqrtf(vals[1] + 1e-6f);
  float bet = beta[row];
  float qnv = qv * qi, knv = kv * ki;
  qn[base] = qnv;
  kn[base] = knv;
  vb[base] = vv * bet;
  kb[base] = knv * bet;
  int b = row >> 12, l = (row >> 2) & 1023, h = row & 3;
  qnbf[((i64)(b * 4 + h) * 1024 + l) * 256 + t] = f2bf(qnv);
}

// ---------------- phase A: per-chunk UT-transform; emits u fp32, w bf16(neg), attn bf16, knT bf16 ----------------
__global__ __launch_bounds__(256) void phaseA_kernel(
    const float* __restrict__ qn, const float* __restrict__ kn,
    const float* __restrict__ vb, const float* __restrict__ kb,
    float* __restrict__ u_g, u16t* __restrict__ w_bf, u16t* __restrict__ attn_bf,
    u16t* __restrict__ knT) {
  __shared__ float KN[32][260];
  __shared__ float Ms[32][32];
  int blk = blockIdx.x, t = threadIdx.x;
  int i = blk & 31, bh = blk >> 5;
  int rbase = ((bh >> 2) * LL + i * 32) * NH + (bh & 3);
  i64 bhn = blk;   // = bh*32 + i
#pragma unroll
  for (int ii = 0; ii < 8; ii++) {
    int fid = t + ii * 256;
    int c = fid >> 6, dq = (fid & 63) << 2;
    *(float4*)&KN[c][dq] = *(const float4*)(kn + (i64)(rbase + c * NH) * 256 + dq);
  }
  __syncthreads();
  int c = t >> 3, e0 = (t & 7) * 4;
  const float* kbp = kb + (i64)(rbase + c * NH) * 256;
  const float* qp = qn + (i64)(rbase + c * NH) * 256;
  float am[4] = {0, 0, 0, 0}, aa[4] = {0, 0, 0, 0};
  for (int d = 0; d < 256; d += 4) {
    float4 kv = *(const float4*)(kbp + d);
    float4 qv = *(const float4*)(qp + d);
#pragma unroll
    for (int z = 0; z < 4; z++) {
      float4 nv = *(const float4*)&KN[e0 + z][d];
      am[z] += kv.x * nv.x + kv.y * nv.y + kv.z * nv.z + kv.w * nv.w;
      aa[z] += qv.x * nv.x + qv.y * nv.y + qv.z * nv.z + qv.w * nv.w;
    }
  }
  {
    uint2 o;
    u16t a0 = (e0 + 0 <= c) ? f2bf(aa[0]) : 0;
    u16t a1 = (e0 + 1 <= c) ? f2bf(aa[1]) : 0;
    u16t a2 = (e0 + 2 <= c) ? f2bf(aa[2]) : 0;
    u16t a3 = (e0 + 3 <= c) ? f2bf(aa[3]) : 0;
    o.x = pk2(a0, a1); o.y = pk2(a2, a3);
    *(uint2*)(attn_bf + bhn * 1024 + c * 32 + e0) = o;
  }
#pragma unroll
  for (int z = 0; z < 4; z++) {
    int e = e0 + z;
    Ms[c][e] = (e < c) ? am[z] : 0.0f;
  }
  __syncthreads();
  // forward substitution, thread = column d
  float uc[32], wc[32];
#pragma unroll
  for (int cc = 0; cc < 32; cc++) {
    float uval = vb[(i64)(rbase + cc * NH) * 256 + t];
    float wval = kb[(i64)(rbase + cc * NH) * 256 + t];
#pragma unroll
    for (int c2 = 0; c2 < cc; c2++) {
      float m = Ms[cc][c2];
      uval -= m * uc[c2];
      wval -= m * wc[c2];
    }
    uc[cc] = uval; wc[cc] = wval;
    u_g[(bhn * 32 + cc) * 256 + t] = uval;
    w_bf[(bhn * 32 + cc) * 256 + t] = f2bf(-wval);
  }
  // emit knT [bhn][d][c] bf16 from the staged KN tile
  int d = t;
  u16t o[32];
#pragma unroll
  for (int cc = 0; cc < 32; cc++) o[cc] = f2bf(KN[cc][d]);
#pragma unroll
  for (int z = 0; z < 4; z++) {
    uint4 vv;
    vv.x = pk2(o[z * 8 + 0], o[z * 8 + 1]);
    vv.y = pk2(o[z * 8 + 2], o[z * 8 + 3]);
    vv.z = pk2(o[z * 8 + 4], o[z * 8 + 5]);
    vv.w = pk2(o[z * 8 + 6], o[z * 8 + 7]);
    *(uint4*)(knT + (bhn * 256 + d) * 32 + z * 8) = vv;
  }
}

// ---------------- fused delta scan: u' + o + S-update in one sequential pass ----------------
// grid 128 = bh(8) x jb(16). Waves 0-1: u' = u - w@S. Waves 2-3: o = q@S + attn@u'.
// All waves: S += knT @ u' (S in fp32 accumulators, bf16 snapshot in LDS).
// NOTE: double-buffer uses two NAMED structs + manual 2x unroll — dynamic
// indexing of the buffers (r4 bug) demotes them to scratch (92 VGPR, 60 MB
// phantom traffic, 18x slowdown).
struct ScanBuf {
  short8 m8[8];   // w rows (waves 0-1) or q rows (waves 2-3)
  f32x4 uc4;      // u c-block (waves 0-1)
  short8 af;      // attn rows (waves 2-3)
  short8 kf[4];   // knT rows
};

__global__ __launch_bounds__(256) void delta_scan_kernel(
    const u16t* __restrict__ wbf, const u16t* __restrict__ knT,
    const float* __restrict__ u_g, const u16t* __restrict__ qnbf,
    const u16t* __restrict__ attnbf,
    float* __restrict__ dlt, u16t* __restrict__ brcat) {
  __shared__ u16t Sbf[16 * 272];   // [j][d] bf16 snapshot
  __shared__ u16t Ubf[16 * 40];    // [j][c] u' chunk
  int t = threadIdx.x, w = t >> 6, lane = t & 63;
  int l15 = lane & 15, quad = lane >> 4;
  int bh = blockIdx.x >> 4, jb = blockIdx.x & 15, j0 = jb * 16;
  int b_ = bh >> 2, h_ = bh & 3;
  bool isU = (w < 2);
  int wc = isU ? w : (w - 2);
  for (int idx = t; idx < 16 * 272; idx += 256) Sbf[idx] = 0;
  f32x4 accS[4] = {};
  __syncthreads();

  auto load_chunk = [&](int i, ScanBuf& B) {
    i64 bhn = (i64)bh * 32 + i;
    const u16t* mbase = isU
        ? wbf + (bhn * 32 + wc * 16 + l15) * 256 + quad * 8
        : qnbf + ((i64)bh * 1024 + i * 32 + wc * 16 + l15) * 256 + quad * 8;
#pragma unroll
    for (int kd = 0; kd < 8; kd++) B.m8[kd] = *(const short8*)(mbase + kd * 32);
    if (isU) {
      int cm = wc * 16 + quad * 4;
#pragma unroll
      for (int r = 0; r < 4; r++)
        B.uc4[r] = u_g[(bhn * 32 + cm + r) * 256 + j0 + l15];
    } else {
      B.af = *(const short8*)(attnbf + bhn * 1024 + (wc * 16 + l15) * 32 + quad * 8);
    }
#pragma unroll
    for (int dt = 0; dt < 4; dt++)
      B.kf[dt] = *(const short8*)(knT + (bhn * 256 + w * 64 + dt * 16 + l15) * 32 + quad * 8);
  };

  auto process = [&](int i, ScanBuf& B) {
    f32x4 zero = {};
    f32x4 cacc = isU ? B.uc4 : zero;
#pragma unroll
    for (int kd = 0; kd < 8; kd++) {
      short8 sf = *(const short8*)&Sbf[l15 * 272 + kd * 32 + quad * 8];
      cacc = MFMA_BF16(B.m8[kd], sf, cacc);
    }
    if (isU) {
      int cm = wc * 16 + quad * 4;
      uint2 o;
      o.x = pk2(f2bf(cacc[0]), f2bf(cacc[1]));
      o.y = pk2(f2bf(cacc[2]), f2bf(cacc[3]));
      *(uint2*)&Ubf[l15 * 40 + cm] = o;
    }
    __syncthreads();
    short8 bu = *(const short8*)&Ubf[l15 * 40 + quad * 8];
    if (!isU) {
      cacc = MFMA_BF16(B.af, bu, cacc);
#pragma unroll
      for (int rg = 0; rg < 4; rg++) {
        int l = i * 32 + wc * 16 + quad * 4 + rg;
        i64 row = ((i64)b_ * 1024 + l) * 4 + h_;
        dlt[row * 256 + j0 + l15] = cacc[rg];
        brcat[row * 1024 + 512 + j0 + l15] = f2bf(cacc[rg]);
      }
    }
#pragma unroll
    for (int dt = 0; dt < 4; dt++) accS[dt] = MFMA_BF16(B.kf[dt], bu, accS[dt]);
#pragma unroll
    for (int dt = 0; dt < 4; dt++) {
      uint2 o;
      o.x = pk2(f2bf(accS[dt][0]), f2bf(accS[dt][1]));
      o.y = pk2(f2bf(accS[dt][2]), f2bf(accS[dt][3]));
      *(uint2*)&Sbf[l15 * 272 + w * 64 + dt * 16 + quad * 4] = o;
    }
    __syncthreads();
  };

  ScanBuf b0, b1;
  load_chunk(0, b0);
#pragma unroll 1
  for (int ii = 0; ii < 16; ii++) {
    int i = ii * 2;
    load_chunk(i + 1, b1);
    process(i, b0);
    if (ii < 15) load_chunk(i + 2, b0);
    process(i + 1, b1);
  }
}

// ---------------- per-head depthwise causal FIR (+ bf16 branch copy) ----------------
__global__ __launch_bounds__(256) void fir_kernel(
    const float* __restrict__ v, const float* __restrict__ f, float* __restrict__ out,
    u16t* __restrict__ brcat, int col0, int K) {
  __shared__ float fb[256 * 31];
  int row = blockIdx.x, t = threadIdx.x;
  int h = row & 3, l = (row >> 2) & (LL - 1);
  for (int idx = t; idx < 256 * K; idx += 256) fb[idx] = f[h * 256 * K + idx];
  __syncthreads();
  float acc = 0.0f;
  int jmin = (K - 1) - l; if (jmin < 0) jmin = 0;
  for (int jj = jmin; jj < K; jj++) {
    int dl = jj - (K - 1);
    acc += fb[t * K + jj] * v[(i64)(row + dl * NH) * 256 + t];
  }
  out[(i64)row * 256 + t] = acc;
  brcat[(i64)row * 1024 + col0 + t] = f2bf(acc);
}

// ---------------- per-(row,branch) stats ----------------
__global__ __launch_bounds__(256) void stats_kernel(
    const float* __restrict__ fs, const float* __restrict__ fl,
    const float* __restrict__ dlt, const float* __restrict__ v, float* __restrict__ stat) {
  int row = blockIdx.x, t = threadIdx.x;
  __shared__ float sc[8];
  __shared__ float scm[4];
  const float* brs[4] = {fs, fl, dlt, v};
#pragma unroll
  for (int p = 0; p < 4; p++) {
    float x = brs[p][(i64)row * 256 + t];
    float vals[2] = {x, x * x};
    block_reduce_sum<2>(vals, sc);
    float m = x;
#pragma unroll
    for (int off = 1; off < 64; off <<= 1) m = fmaxf(m, __shfl_xor(m, off));
    int lane = t & 63, wid = t >> 6;
    if (lane == 0) scm[wid] = m;
    __syncthreads();
    if (t == 0) {
      float mx = fmaxf(fmaxf(scm[0], scm[1]), fmaxf(scm[2], scm[3]));
      stat[row * 12 + p * 3 + 0] = vals[0] * (1.0f / 256.0f);
      stat[row * 12 + p * 3 + 1] = sqrtf(fmaxf(vals[1] * (1.0f / 256.0f), 1e-8f));
      stat[row * 12 + p * 3 + 2] = mx;
    }
    __syncthreads();
  }
}

// ---------------- W1 stat-block column sums (96 blocks, atomic accumulate) ----------------
__global__ __launch_bounds__(256) void wsum_kernel(const float* __restrict__ W1, float* __restrict__ Wsum) {
  int blk = blockIdx.x;        // 96 = 12 stats * 8 row-chunks
  int s = blk >> 3, rc = blk & 7;
  int t = threadIdx.x;
  const float* p = W1 + (i64)(1024 + s * 256 + rc * 32) * 512;
  float a0 = 0.0f, a1 = 0.0f;
  for (int r = 0; r < 32; r++) {
    a0 += p[(i64)r * 512 + t];
    a1 += p[(i64)r * 512 + t + 256];
  }
  atomicAdd(&Wsum[s * 512 + t], a0);
  atomicAdd(&Wsum[s * 512 + t + 256], a1);
}

// ---------------- gate MLP tail ----------------
__global__ __launch_bounds__(256) void gate_kernel(
    const float* __restrict__ hbase, const float* __restrict__ brW,
    const float* __restrict__ stat, const float* __restrict__ wsum,
    const float* __restrict__ gb1, const float* __restrict__ gW2,
    const float* __restrict__ gb2, const float* __restrict__ temp,
    const float* __restrict__ epsf, float* __restrict__ gw) {
  int row = blockIdx.x, t = threadIdx.x;
  int bl = row >> 2, h = row & 3;
  __shared__ float sc[16];
  float st[12];
#pragma unroll
  for (int s = 0; s < 12; s++) st[s] = stat[row * 12 + s];
  float lg[4] = {0, 0, 0, 0};
  for (int o = t; o < 512; o += 256) {
    float hm = hbase[(i64)bl * 512 + o] + brW[(i64)row * 512 + o] + gb1[o];
#pragma unroll
    for (int s = 0; s < 12; s++) hm += st[s] * wsum[s * 512 + o];
    float ge = 0.5f * hm * (1.0f + erff(hm * 0.70710678118654752f));
    float4 w2 = *(const float4*)(gW2 + o * 4);
    lg[0] += ge * w2.x; lg[1] += ge * w2.y; lg[2] += ge * w2.z; lg[3] += ge * w2.w;
  }
  block_reduce_sum<4>(lg, sc);
  if (t == 0) {
    float tt = fminf(fmaxf(temp[h], 0.2f), 10.0f);
    float l0 = (lg[0] + gb2[0]) / tt;
    float l1 = (lg[1] + gb2[1]) / tt;
    float l2 = (lg[2] + gb2[2]) / tt;
    float l3 = (lg[3] + gb2[3]) / tt;
    float m = fmaxf(fmaxf(l0, l1), fmaxf(l2, l3));
    float e0 = expf(l0 - m), e1 = expf(l1 - m), e2 = expf(l2 - m), e3 = expf(l3 - m);
    float ssum = e0 + e1 + e2 + e3;
    float w0 = e0 / ssum, w1 = e1 / ssum, w2 = e2 / ssum, w3 = e3 / ssum;
    w0 = fmaxf(w0, fminf(fmaxf(epsf[h * 4 + 0], 1e-7f), 0.1f));
    w1 = fmaxf(w1, fminf(fmaxf(epsf[h * 4 + 1], 1e-7f), 0.1f));
    w2 = fmaxf(w2, fminf(fmaxf(epsf[h * 4 + 2], 1e-7f), 0.1f));
    w3 = fmaxf(w3, fminf(fmaxf(epsf[h * 4 + 3], 1e-7f), 0.1f));
    float s2 = w0 + w1 + w2 + w3;
    gw[row * 4 + 0] = w0 / s2;
    gw[row * 4 + 1] = w1 / s2;
    gw[row * 4 + 2] = w2 / s2;
    gw[row * 4 + 3] = w3 / s2;
  }
}

// ---------------- weighted mix + RMS norm -> bf16 [2048][1024] ----------------
__global__ __launch_bounds__(256) void mix_kernel(
    const float* __restrict__ fs, const float* __restrict__ fl,
    const float* __restrict__ dlt, const float* __restrict__ v,
    const float* __restrict__ gw, const float* __restrict__ onw, u16t* __restrict__ out) {
  int row = blockIdx.x, t = threadIdx.x;
  __shared__ float sc[4];
  i64 base = (i64)row * 256 + t;
  float4 wv = *(const float4*)(gw + row * 4);
  float o = wv.x * fs[base] + wv.y * fl[base] + wv.z * dlt[base] + wv.w * v[base];
  float vals[1] = {o * o};
  block_reduce_sum<1>(vals, sc);
  float scale = rsqrtf(vals[0] * (1.0f / 256.0f) + 1e-5f);
  out[(i64)(row >> 2) * 1024 + (row & 3) * 256 + t] = f2bf(o * scale * onw[t]);
}

extern "C" void kernel_launch(void* const* d_in, const int* in_sizes, int n_in,
                              void* d_out, int out_size, void* d_ws, size_t ws_size,
                              hipStream_t stream) {
  (void)in_sizes; (void)n_in; (void)out_size; (void)ws_size;
  const float* x    = (const float*)d_in[0];
  const float* Wq   = (const float*)d_in[1];
  const float* Wk   = (const float*)d_in[2];
  const float* Wv   = (const float*)d_in[3];
  const float* Wb   = (const float*)d_in[4];
  const float* qcw  = (const float*)d_in[5];
  const float* kcw  = (const float*)d_in[6];
  const float* vcw  = (const float*)d_in[7];
  const float* gW1  = (const float*)d_in[8];
  const float* gb1  = (const float*)d_in[9];
  const float* gW2  = (const float*)d_in[10];
  const float* gb2  = (const float*)d_in[11];
  const float* temp = (const float*)d_in[12];
  const float* epsf = (const float*)d_in[13];
  const float* onw  = (const float*)d_in[14];
  const float* Wo   = (const float*)d_in[15];
  const float* firs = (const float*)d_in[16];
  const float* firl = (const float*)d_in[17];
  float* out = (float*)d_out;

  float* ws = (float*)d_ws;
  // ---- workspace map (float offsets) ----
  // [0, 6291456): qkv_pre (steps 2-3) -> branchW@0 + hbase@4194304 (steps 12+)
  float* qkv_pre  = ws + 0;                       // 2048*3072 fp32
  float* branchW  = ws + 0;                       // 8192*512 fp32
  float* hbase    = ws + 4194304;                 // 2048*512 fp32
  u16t*  brcat    = (u16t*)(ws + 6291456);        // 8192*1024 bf16 (own region)
  float* qbuf     = ws + 10485760; float* qn = qbuf;
  float* kbuf     = ws + 12582912; float* kn = kbuf;
  float* vbuf     = ws + 14680064;
  float* vb       = ws + 16777216;                // dead after phaseA
  u16t*  omix_bf  = (u16t*)(ws + 16777216);       // 2048*1024 bf16 (step 16+)
  u16t*  W1hT     = (u16t*)(ws + 17825792);       // 512*1024 bf16 (step 12+)
  u16t*  W1bT     = (u16t*)(ws + 18087936);       // 512*1024 bf16
  u16t*  WoT      = (u16t*)(ws + 18350080);       // 1024*1024 bf16
  float* kb       = ws + 18874368;                // dead after phaseA
  float* dlt      = ws + 18874368;                // scan output (step 8+)
  float* u_g      = ws + 20971520;                // phaseA -> scan
  u16t*  w_bf     = (u16t*)(ws + 23068672);       // negated w bf16
  u16t*  qn_bf    = (u16t*)(ws + 24117248);
  u16t*  knT      = (u16t*)(ws + 25165824);
  u16t*  attn_bf  = (u16t*)(ws + 26214400);
  float* fs       = ws + 26345472;
  float* fl       = ws + 28442624;
  u16t*  xbf      = (u16t*)(ws + 30539776);
  u16t*  WqkvT    = (u16t*)(ws + 31588352);       // 3072*1024 bf16
  float* betab    = ws + 33161216;
  float* stat     = ws + 33169408;
  float* wsum     = ws + 33267712;                // 12*512 fp32
  float* gw       = ws + 33273856;

  // 1) casts + QKV weight transposes
  castbf_kernel<<<2048, 256, 0, stream>>>(x, xbf, 524288);
  transcast_kernel<<<dim3(32, 32), 256, 0, stream>>>(Wq, 1024, 0, WqkvT, 1024);
  transcast_kernel<<<dim3(32, 32), 256, 0, stream>>>(Wk, 1024, 0, WqkvT + 1024 * 1024, 1024);
  transcast_kernel<<<dim3(32, 32), 256, 0, stream>>>(Wv, 1024, 0, WqkvT + 2048 * 1024, 1024);
  // 2) QKV GEMM
  gemm_bt_kernel<<<dim3(24, 16), 256, 0, stream>>>(xbf, WqkvT, qkv_pre, 1024, 3072);
  // 3) fused conv+silu (v also -> brcat col 768)
  conv_silu3_kernel<<<24576, 256, 0, stream>>>(qkv_pre, qcw, kcw, vcw, qbuf, kbuf, vbuf, brcat);
  // 4) beta + preprocess (emits qn_bf)
  beta_kernel<<<2048, 256, 0, stream>>>(x, Wb, betab);
  preprocess_kernel<<<8192, 256, 0, stream>>>(qbuf, kbuf, vbuf, betab, qn, kn, vb, kb, qn_bf);
  // 5) phase A (fp32 substitution; emits u fp32, w/attn/knT bf16)
  phaseA_kernel<<<256, 256, 0, stream>>>(qn, kn, vb, kb, u_g, w_bf, attn_bf, knT);
  // 6) fused delta scan (emits dlt fp32 + brcat col 512)
  delta_scan_kernel<<<128, 256, 0, stream>>>(w_bf, knT, u_g, qn_bf, attn_bf, dlt, brcat);
  // 7) FIR branches (emit fp32 + brcat cols 0 / 256)
  fir_kernel<<<8192, 256, 0, stream>>>(vbuf, firs, fs, brcat, 0, 3);
  fir_kernel<<<8192, 256, 0, stream>>>(vbuf, firl, fl, brcat, 256, 31);
  // 8) stats + wsum
  stats_kernel<<<8192, 256, 0, stream>>>(fs, fl, dlt, vbuf, stat);
  hipMemsetAsync(wsum, 0, 12 * 512 * sizeof(float), stream);
  wsum_kernel<<<96, 256, 0, stream>>>(gW1, wsum);
  // 9) gate GEMMs
  transcast_kernel<<<dim3(16, 32), 256, 0, stream>>>(gW1, 512, 0, W1hT, 1024);
  transcast_kernel<<<dim3(16, 32), 256, 0, stream>>>(gW1 + (i64)4096 * 512, 512, 0, W1bT, 1024);
  gemm_bt_kernel<<<dim3(4, 16), 256, 0, stream>>>(xbf, W1hT, hbase, 1024, 512);
  gemm_bt_kernel<<<dim3(4, 64), 256, 0, stream>>>(brcat, W1bT, branchW, 1024, 512);
  // 10) gate tail + mix (mix emits bf16 directly)
  gate_kernel<<<8192, 256, 0, stream>>>(hbase, branchW, stat, wsum, gb1, gW2, gb2, temp, epsf, gw);
  mix_kernel<<<8192, 256, 0, stream>>>(fs, fl, dlt, vbuf, gw, onw, omix_bf);
  // 11) final projection
  transcast_kernel<<<dim3(32, 32), 256, 0, stream>>>(Wo, 1024, 0, WoT, 1024);
  gemm_bt_kernel<<<dim3(8, 16), 256, 0, stream>>>(omix_bf, WoT, out, 1024, 1024);
}

// Round 6
// 430.642 us; speedup vs baseline: 3.6191x; 1.1001x over previous
//
#include <hip/hip_runtime.h>
#include <math.h>

// Problem constants
#define BB 2
#define LL 1024
#define HIDD 1024
#define NH 4
#define DD 256
#define NCH 32
#define ROWS 2048
#define HROWS 8192

typedef long long i64;
typedef unsigned short u16t;
typedef unsigned int u32t;
typedef __attribute__((ext_vector_type(8))) short short8;
typedef __attribute__((ext_vector_type(4))) float f32x4;
#define MFMA_BF16(a, b, c) __builtin_amdgcn_mfma_f32_16x16x32_bf16(a, b, c, 0, 0, 0)

__device__ __forceinline__ float sigmoidf_(float x) { return 1.0f / (1.0f + expf(-x)); }

__device__ __forceinline__ u16t f2bf(float f) {
  u32t u = __float_as_uint(f);
  u = u + 0x7FFFu + ((u >> 16) & 1u);
  return (u16t)(u >> 16);
}
__device__ __forceinline__ u32t pk2(u16t a, u16t b) { return (u32t)a | ((u32t)b << 16); }

// ---------------- block reduction helper (blockDim == 256) ----------------
template<int N>
__device__ __forceinline__ void block_reduce_sum(float* v, float* scratch) {
  int lane = threadIdx.x & 63, wid = threadIdx.x >> 6;
#pragma unroll
  for (int i = 0; i < N; i++) {
    float x = v[i];
#pragma unroll
    for (int off = 1; off < 64; off <<= 1) x += __shfl_xor(x, off);
    if (lane == 0) scratch[wid * N + i] = x;
  }
  __syncthreads();
#pragma unroll
  for (int i = 0; i < N; i++)
    v[i] = scratch[i] + scratch[N + i] + scratch[2 * N + i] + scratch[3 * N + i];
  __syncthreads();
}

// ---------------- cast fp32 -> bf16 ----------------
__global__ __launch_bounds__(256) void castbf_kernel(
    const float* __restrict__ in, u16t* __restrict__ out, int n4) {
  int idx = blockIdx.x * 256 + threadIdx.x;
  if (idx >= n4) return;
  int e = idx * 4;
  float4 v = *(const float4*)(in + (i64)e);
  uint2 o;
  o.x = pk2(f2bf(v.x), f2bf(v.y));
  o.y = pk2(f2bf(v.z), f2bf(v.w));
  *(uint2*)(out + (i64)e) = o;
}

// ---------------- transpose + cast: in fp32 [K][N] -> out bf16 [N][K] ----------------
__global__ __launch_bounds__(256) void transcast_kernel(
    const float* __restrict__ in, int ldin, int col0,
    u16t* __restrict__ out, int ldout) {
  __shared__ float tile[32][33];
  int tx = threadIdx.x & 31, ty = threadIdx.x >> 5;
  int nb = blockIdx.x * 32, kb = blockIdx.y * 32;
#pragma unroll
  for (int r = 0; r < 4; r++)
    tile[ty + r * 8][tx] = in[(i64)(kb + ty + r * 8) * ldin + col0 + nb + tx];
  __syncthreads();
#pragma unroll
  for (int r = 0; r < 4; r++)
    out[(i64)(nb + ty + r * 8) * ldout + kb + tx] = f2bf(tile[tx][ty + r * 8]);
}

// ---------------- bf16 MFMA GEMM: A[M][K] bf16, B[N][K] bf16, C[M][N] fp32 ----------------
__global__ __launch_bounds__(256) void gemm_bt_kernel(
    const u16t* __restrict__ A, const u16t* __restrict__ B,
    float* __restrict__ C, int K, int ldc) {
  __shared__ u16t As[128 * 40];
  __shared__ u16t Bs[128 * 40];
  int t = threadIdx.x;
  int n0 = blockIdx.x * 128, m0 = blockIdx.y * 128;
  int w = t >> 6, lane = t & 63;
  int l15 = lane & 15, quad = lane >> 4;
  int wm = (w & 1) * 64, wn = (w >> 1) * 64;
  f32x4 acc[4][4] = {};
  int srow = t >> 1, shalf = (t & 1) * 16;
  const u16t* Ag = A + (i64)(m0 + srow) * K + shalf;
  const u16t* Bg = B + (i64)(n0 + srow) * K + shalf;
  for (int k0 = 0; k0 < K; k0 += 32) {
    *(uint4*)&As[srow * 40 + shalf] = *(const uint4*)(Ag + k0);
    *(uint4*)&As[srow * 40 + shalf + 8] = *(const uint4*)(Ag + k0 + 8);
    *(uint4*)&Bs[srow * 40 + shalf] = *(const uint4*)(Bg + k0);
    *(uint4*)&Bs[srow * 40 + shalf + 8] = *(const uint4*)(Bg + k0 + 8);
    __syncthreads();
    short8 a[4], b[4];
#pragma unroll
    for (int mt = 0; mt < 4; mt++)
      a[mt] = *(const short8*)&As[(wm + mt * 16 + l15) * 40 + quad * 8];
#pragma unroll
    for (int nt = 0; nt < 4; nt++)
      b[nt] = *(const short8*)&Bs[(wn + nt * 16 + l15) * 40 + quad * 8];
#pragma unroll
    for (int mt = 0; mt < 4; mt++)
#pragma unroll
      for (int nt = 0; nt < 4; nt++)
        acc[mt][nt] = MFMA_BF16(a[mt], b[nt], acc[mt][nt]);
    __syncthreads();
  }
#pragma unroll
  for (int mt = 0; mt < 4; mt++) {
    int r0 = m0 + wm + mt * 16 + quad * 4;
#pragma unroll
    for (int nt = 0; nt < 4; nt++) {
      int cc = n0 + wn + nt * 16 + l15;
#pragma unroll
      for (int rg = 0; rg < 4; rg++)
        C[(i64)(r0 + rg) * ldc + cc] = acc[mt][nt][rg];
    }
  }
}

// ---------------- fused causal depthwise conv (K=4) + silu for q,k,v ----------------
__global__ __launch_bounds__(256) void conv_silu3_kernel(
    const float* __restrict__ pre, const float* __restrict__ qw,
    const float* __restrict__ kw, const float* __restrict__ vw,
    float* __restrict__ qo, float* __restrict__ ko, float* __restrict__ vo,
    u16t* __restrict__ brcat) {
  int seg = blockIdx.x >> 13;
  int idx = (blockIdx.x & 8191) * 256 + threadIdx.x;
  int c = idx & 1023, row = idx >> 10, l = row & 1023;
  const float* w = seg == 0 ? qw : seg == 1 ? kw : vw;
  float* out = seg == 0 ? qo : seg == 1 ? ko : vo;
  float4 wv = *(const float4*)(w + c * 4);
  const float* base = pre + (i64)row * 3072 + (seg << 10) + c;
  float acc = wv.w * base[0];
  if (l >= 1) acc += wv.z * base[-3072];
  if (l >= 2) acc += wv.y * base[-2 * 3072];
  if (l >= 3) acc += wv.x * base[-3 * 3072];
  float r = acc * sigmoidf_(acc);
  out[(i64)row * 1024 + c] = r;
  if (seg == 2)
    brcat[((i64)row * 4 + (c >> 8)) * 1024 + 768 + (c & 255)] = f2bf(r);
}

// ---------------- beta = sigmoid(x @ Wb) ----------------
__global__ __launch_bounds__(256) void beta_kernel(
    const float* __restrict__ x, const float* __restrict__ Wb, float* __restrict__ beta) {
  int row = blockIdx.x, t = threadIdx.x;
  __shared__ float sc[16];
  float a[4] = {0, 0, 0, 0};
  for (int c = t; c < 1024; c += 256) {
    float xv = x[(i64)row * 1024 + c];
    float4 wv = *(const float4*)(Wb + c * 4);
    a[0] += xv * wv.x; a[1] += xv * wv.y; a[2] += xv * wv.z; a[3] += xv * wv.w;
  }
  block_reduce_sum<4>(a, sc);
  if (t == 0) {
#pragma unroll
    for (int g = 0; g < 4; g++) beta[row * 4 + g] = sigmoidf_(a[g]);
  }
}

// ---------------- l2norm(q,k), v*beta, kn*beta; qn also emitted bf16 in delta layout ----------------
__global__ __launch_bounds__(256) void preprocess_kernel(
    const float* __restrict__ q, const float* __restrict__ k, const float* __restrict__ v,
    const float* __restrict__ beta, float* __restrict__ qn, float* __restrict__ kn,
    float* __restrict__ vb, float* __restrict__ kb, u16t* __restrict__ qnbf) {
  int row = blockIdx.x, t = threadIdx.x;   // row = (b*1024+l)*4+h
  __shared__ float sc[8];
  i64 base = (i64)row * 256 + t;
  float qv = q[base], kv = k[base], vv = v[base];
  float vals[2] = {qv * qv, kv * kv};
  block_reduce_sum<2>(vals, sc);
  float qi = rsqrtf(vals[0] + 1e-6f), ki = rsqrtf(vals[1] + 1e-6f);
  float bet = beta[row];
  float qnv = qv * qi, knv = kv * ki;
  qn[base] = qnv;
  kn[base] = knv;
  vb[base] = vv * bet;
  kb[base] = knv * bet;
  int b = row >> 12, l = (row >> 2) & 1023, h = row & 3;
  qnbf[((i64)(b * 4 + h) * 1024 + l) * 256 + t] = f2bf(qnv);
}

// ---------------- phase A: per-chunk UT-transform; emits u fp32, w bf16(neg), attn bf16, knT bf16 ----------------
__global__ __launch_bounds__(256) void phaseA_kernel(
    const float* __restrict__ qn, const float* __restrict__ kn,
    const float* __restrict__ vb, const float* __restrict__ kb,
    float* __restrict__ u_g, u16t* __restrict__ w_bf, u16t* __restrict__ attn_bf,
    u16t* __restrict__ knT) {
  __shared__ float KN[32][260];
  __shared__ float Ms[32][32];
  int blk = blockIdx.x, t = threadIdx.x;
  int i = blk & 31, bh = blk >> 5;
  int rbase = ((bh >> 2) * LL + i * 32) * NH + (bh & 3);
  i64 bhn = blk;   // = bh*32 + i
#pragma unroll
  for (int ii = 0; ii < 8; ii++) {
    int fid = t + ii * 256;
    int c = fid >> 6, dq = (fid & 63) << 2;
    *(float4*)&KN[c][dq] = *(const float4*)(kn + (i64)(rbase + c * NH) * 256 + dq);
  }
  __syncthreads();
  int c = t >> 3, e0 = (t & 7) * 4;
  const float* kbp = kb + (i64)(rbase + c * NH) * 256;
  const float* qp = qn + (i64)(rbase + c * NH) * 256;
  float am[4] = {0, 0, 0, 0}, aa[4] = {0, 0, 0, 0};
  for (int d = 0; d < 256; d += 4) {
    float4 kv = *(const float4*)(kbp + d);
    float4 qv = *(const float4*)(qp + d);
#pragma unroll
    for (int z = 0; z < 4; z++) {
      float4 nv = *(const float4*)&KN[e0 + z][d];
      am[z] += kv.x * nv.x + kv.y * nv.y + kv.z * nv.z + kv.w * nv.w;
      aa[z] += qv.x * nv.x + qv.y * nv.y + qv.z * nv.z + qv.w * nv.w;
    }
  }
  {
    uint2 o;
    u16t a0 = (e0 + 0 <= c) ? f2bf(aa[0]) : 0;
    u16t a1 = (e0 + 1 <= c) ? f2bf(aa[1]) : 0;
    u16t a2 = (e0 + 2 <= c) ? f2bf(aa[2]) : 0;
    u16t a3 = (e0 + 3 <= c) ? f2bf(aa[3]) : 0;
    o.x = pk2(a0, a1); o.y = pk2(a2, a3);
    *(uint2*)(attn_bf + bhn * 1024 + c * 32 + e0) = o;
  }
#pragma unroll
  for (int z = 0; z < 4; z++) {
    int e = e0 + z;
    Ms[c][e] = (e < c) ? am[z] : 0.0f;
  }
  __syncthreads();
  // forward substitution, thread = column d
  float uc[32], wc[32];
#pragma unroll
  for (int cc = 0; cc < 32; cc++) {
    float uval = vb[(i64)(rbase + cc * NH) * 256 + t];
    float wval = kb[(i64)(rbase + cc * NH) * 256 + t];
#pragma unroll
    for (int c2 = 0; c2 < cc; c2++) {
      float m = Ms[cc][c2];
      uval -= m * uc[c2];
      wval -= m * wc[c2];
    }
    uc[cc] = uval; wc[cc] = wval;
    u_g[(bhn * 32 + cc) * 256 + t] = uval;
    w_bf[(bhn * 32 + cc) * 256 + t] = f2bf(-wval);
  }
  // emit knT [bhn][d][c] bf16 from the staged KN tile
  int d = t;
  u16t o[32];
#pragma unroll
  for (int cc = 0; cc < 32; cc++) o[cc] = f2bf(KN[cc][d]);
#pragma unroll
  for (int z = 0; z < 4; z++) {
    uint4 vv;
    vv.x = pk2(o[z * 8 + 0], o[z * 8 + 1]);
    vv.y = pk2(o[z * 8 + 2], o[z * 8 + 3]);
    vv.z = pk2(o[z * 8 + 4], o[z * 8 + 5]);
    vv.w = pk2(o[z * 8 + 6], o[z * 8 + 7]);
    *(uint4*)(knT + (bhn * 256 + d) * 32 + z * 8) = vv;
  }
}

// ---------------- fused delta scan ----------------
// grid 128 = jb(16) x bh(8), bh = blk&7 so all 16 jb-blocks of a head land on
// one XCD (L2 reuse of the shared w/knT/qn/attn streams). Sbf row stride 264
// (dword-stride 132 === 4 mod 32 -> balanced banks). Named double-buffer
// structs (dynamic indexing demotes to scratch - r4 bug).
#define SROW 264
struct ScanBuf {
  short8 m8[8];   // w rows (waves 0-1) or q rows (waves 2-3)
  f32x4 uc4;      // u c-block (waves 0-1)
  short8 af;      // attn rows (waves 2-3)
  short8 kf[4];   // knT rows
};

__global__ __launch_bounds__(256) void delta_scan_kernel(
    const u16t* __restrict__ wbf, const u16t* __restrict__ knT,
    const float* __restrict__ u_g, const u16t* __restrict__ qnbf,
    const u16t* __restrict__ attnbf,
    float* __restrict__ dlt, u16t* __restrict__ brcat) {
  __shared__ u16t Sbf[16 * SROW];  // [j][d] bf16 snapshot
  __shared__ u16t Ubf[16 * 40];    // [j][c] u' chunk
  int t = threadIdx.x, w = t >> 6, lane = t & 63;
  int l15 = lane & 15, quad = lane >> 4;
  int bh = blockIdx.x & 7, jb = blockIdx.x >> 3, j0 = jb * 16;
  int b_ = bh >> 2, h_ = bh & 3;
  bool isU = (w < 2);
  int wc = isU ? w : (w - 2);
  for (int idx = t; idx < 16 * SROW; idx += 256) Sbf[idx] = 0;
  f32x4 accS[4] = {};
  __syncthreads();

  auto load_chunk = [&](int i, ScanBuf& B) {
    i64 bhn = (i64)bh * 32 + i;
    const u16t* mbase = isU
        ? wbf + (bhn * 32 + wc * 16 + l15) * 256 + quad * 8
        : qnbf + ((i64)bh * 1024 + i * 32 + wc * 16 + l15) * 256 + quad * 8;
#pragma unroll
    for (int kd = 0; kd < 8; kd++) B.m8[kd] = *(const short8*)(mbase + kd * 32);
    if (isU) {
      int cm = wc * 16 + quad * 4;
#pragma unroll
      for (int r = 0; r < 4; r++)
        B.uc4[r] = u_g[(bhn * 32 + cm + r) * 256 + j0 + l15];
    } else {
      B.af = *(const short8*)(attnbf + bhn * 1024 + (wc * 16 + l15) * 32 + quad * 8);
    }
#pragma unroll
    for (int dt = 0; dt < 4; dt++)
      B.kf[dt] = *(const short8*)(knT + (bhn * 256 + w * 64 + dt * 16 + l15) * 32 + quad * 8);
  };

  auto process = [&](int i, ScanBuf& B) {
    // phase 1: two parallel 4-deep MFMA chains over the K=256 reduction
    f32x4 zero = {};
    f32x4 ca = isU ? B.uc4 : zero;
    f32x4 cb = zero;
#pragma unroll
    for (int kd = 0; kd < 4; kd++) {
      short8 sfa = *(const short8*)&Sbf[l15 * SROW + kd * 32 + quad * 8];
      short8 sfb = *(const short8*)&Sbf[l15 * SROW + (kd + 4) * 32 + quad * 8];
      ca = MFMA_BF16(B.m8[kd], sfa, ca);
      cb = MFMA_BF16(B.m8[kd + 4], sfb, cb);
    }
    f32x4 cacc;
#pragma unroll
    for (int r = 0; r < 4; r++) cacc[r] = ca[r] + cb[r];
    if (isU) {
      int cm = wc * 16 + quad * 4;
      uint2 o;
      o.x = pk2(f2bf(cacc[0]), f2bf(cacc[1]));
      o.y = pk2(f2bf(cacc[2]), f2bf(cacc[3]));
      *(uint2*)&Ubf[l15 * 40 + cm] = o;
    }
    __syncthreads();
    short8 bu = *(const short8*)&Ubf[l15 * 40 + quad * 8];
    if (!isU) {
      cacc = MFMA_BF16(B.af, bu, cacc);
#pragma unroll
      for (int rg = 0; rg < 4; rg++) {
        int l = i * 32 + wc * 16 + quad * 4 + rg;
        i64 row = ((i64)b_ * 1024 + l) * 4 + h_;
        dlt[row * 256 + j0 + l15] = cacc[rg];
        brcat[row * 1024 + 512 + j0 + l15] = f2bf(cacc[rg]);
      }
    }
#pragma unroll
    for (int dt = 0; dt < 4; dt++) accS[dt] = MFMA_BF16(B.kf[dt], bu, accS[dt]);
#pragma unroll
    for (int dt = 0; dt < 4; dt++) {
      uint2 o;
      o.x = pk2(f2bf(accS[dt][0]), f2bf(accS[dt][1]));
      o.y = pk2(f2bf(accS[dt][2]), f2bf(accS[dt][3]));
      *(uint2*)&Sbf[l15 * SROW + w * 64 + dt * 16 + quad * 4] = o;
    }
    __syncthreads();
  };

  ScanBuf b0, b1;
  load_chunk(0, b0);
#pragma unroll 1
  for (int ii = 0; ii < 16; ii++) {
    int i = ii * 2;
    load_chunk(i + 1, b1);
    process(i, b0);
    if (ii < 15) load_chunk(i + 2, b0);
    process(i + 1, b1);
  }
}

// ---------------- fused FIR (K=3 and K=31) with register sliding window ----------------
// grid 512 = (b,h,lc): 16 l-outputs per block, thread = d. Window + filters in
// registers: 46 loads per 16 outputs instead of 34 loads per output.
__global__ __launch_bounds__(256) void fir2_kernel(
    const float* __restrict__ v, const float* __restrict__ f_s, const float* __restrict__ f_l,
    float* __restrict__ fs, float* __restrict__ fl, u16t* __restrict__ brcat) {
  int blk = blockIdx.x, t = threadIdx.x;
  int b = blk >> 8, h = (blk >> 6) & 3, lc = blk & 63;
  int l0 = lc * 16;
  float flw[31], fsw[3];
  const float* flp = f_l + ((i64)h * 256 + t) * 31;
#pragma unroll
  for (int j = 0; j < 31; j++) flw[j] = flp[j];
  const float* fsp = f_s + ((i64)h * 256 + t) * 3;
#pragma unroll
  for (int j = 0; j < 3; j++) fsw[j] = fsp[j];
  float win[46];
#pragma unroll
  for (int r = 0; r < 46; r++) {
    int l = l0 - 30 + r;
    win[r] = (l >= 0) ? v[(((i64)b * 1024 + l) * 4 + h) * 256 + t] : 0.0f;
  }
#pragma unroll
  for (int i = 0; i < 16; i++) {
    float al = 0.0f;
#pragma unroll
    for (int j = 0; j < 31; j++) al += flw[j] * win[i + j];
    float as = fsw[0] * win[i + 28] + fsw[1] * win[i + 29] + fsw[2] * win[i + 30];
    i64 row = ((i64)b * 1024 + (l0 + i)) * 4 + h;
    fs[row * 256 + t] = as;
    fl[row * 256 + t] = al;
    brcat[row * 1024 + t] = f2bf(as);
    brcat[row * 1024 + 256 + t] = f2bf(al);
  }
}

// ---------------- per-(row,branch) stats ----------------
__global__ __launch_bounds__(256) void stats_kernel(
    const float* __restrict__ fs, const float* __restrict__ fl,
    const float* __restrict__ dlt, const float* __restrict__ v, float* __restrict__ stat) {
  int row = blockIdx.x, t = threadIdx.x;
  __shared__ float sc[8];
  __shared__ float scm[4];
  const float* brs[4] = {fs, fl, dlt, v};
#pragma unroll
  for (int p = 0; p < 4; p++) {
    float x = brs[p][(i64)row * 256 + t];
    float vals[2] = {x, x * x};
    block_reduce_sum<2>(vals, sc);
    float m = x;
#pragma unroll
    for (int off = 1; off < 64; off <<= 1) m = fmaxf(m, __shfl_xor(m, off));
    int lane = t & 63, wid = t >> 6;
    if (lane == 0) scm[wid] = m;
    __syncthreads();
    if (t == 0) {
      float mx = fmaxf(fmaxf(scm[0], scm[1]), fmaxf(scm[2], scm[3]));
      stat[row * 12 + p * 3 + 0] = vals[0] * (1.0f / 256.0f);
      stat[row * 12 + p * 3 + 1] = sqrtf(fmaxf(vals[1] * (1.0f / 256.0f), 1e-8f));
      stat[row * 12 + p * 3 + 2] = mx;
    }
    __syncthreads();
  }
}

// ---------------- W1 stat-block column sums (96 blocks, atomic accumulate) ----------------
__global__ __launch_bounds__(256) void wsum_kernel(const float* __restrict__ W1, float* __restrict__ Wsum) {
  int blk = blockIdx.x;        // 96 = 12 stats * 8 row-chunks
  int s = blk >> 3, rc = blk & 7;
  int t = threadIdx.x;
  const float* p = W1 + (i64)(1024 + s * 256 + rc * 32) * 512;
  float a0 = 0.0f, a1 = 0.0f;
  for (int r = 0; r < 32; r++) {
    a0 += p[(i64)r * 512 + t];
    a1 += p[(i64)r * 512 + t + 256];
  }
  atomicAdd(&Wsum[s * 512 + t], a0);
  atomicAdd(&Wsum[s * 512 + t + 256], a1);
}

// ---------------- gate MLP tail ----------------
__global__ __launch_bounds__(256) void gate_kernel(
    const float* __restrict__ hbase, const float* __restrict__ brW,
    const float* __restrict__ stat, const float* __restrict__ wsum,
    const float* __restrict__ gb1, const float* __restrict__ gW2,
    const float* __restrict__ gb2, const float* __restrict__ temp,
    const float* __restrict__ epsf, float* __restrict__ gw) {
  int row = blockIdx.x, t = threadIdx.x;
  int bl = row >> 2, h = row & 3;
  __shared__ float sc[16];
  float st[12];
#pragma unroll
  for (int s = 0; s < 12; s++) st[s] = stat[row * 12 + s];
  float lg[4] = {0, 0, 0, 0};
  for (int o = t; o < 512; o += 256) {
    float hm = hbase[(i64)bl * 512 + o] + brW[(i64)row * 512 + o] + gb1[o];
#pragma unroll
    for (int s = 0; s < 12; s++) hm += st[s] * wsum[s * 512 + o];
    float ge = 0.5f * hm * (1.0f + erff(hm * 0.70710678118654752f));
    float4 w2 = *(const float4*)(gW2 + o * 4);
    lg[0] += ge * w2.x; lg[1] += ge * w2.y; lg[2] += ge * w2.z; lg[3] += ge * w2.w;
  }
  block_reduce_sum<4>(lg, sc);
  if (t == 0) {
    float tt = fminf(fmaxf(temp[h], 0.2f), 10.0f);
    float l0 = (lg[0] + gb2[0]) / tt;
    float l1 = (lg[1] + gb2[1]) / tt;
    float l2 = (lg[2] + gb2[2]) / tt;
    float l3 = (lg[3] + gb2[3]) / tt;
    float m = fmaxf(fmaxf(l0, l1), fmaxf(l2, l3));
    float e0 = expf(l0 - m), e1 = expf(l1 - m), e2 = expf(l2 - m), e3 = expf(l3 - m);
    float ssum = e0 + e1 + e2 + e3;
    float w0 = e0 / ssum, w1 = e1 / ssum, w2 = e2 / ssum, w3 = e3 / ssum;
    w0 = fmaxf(w0, fminf(fmaxf(epsf[h * 4 + 0], 1e-7f), 0.1f));
    w1 = fmaxf(w1, fminf(fmaxf(epsf[h * 4 + 1], 1e-7f), 0.1f));
    w2 = fmaxf(w2, fminf(fmaxf(epsf[h * 4 + 2], 1e-7f), 0.1f));
    w3 = fmaxf(w3, fminf(fmaxf(epsf[h * 4 + 3], 1e-7f), 0.1f));
    float s2 = w0 + w1 + w2 + w3;
    gw[row * 4 + 0] = w0 / s2;
    gw[row * 4 + 1] = w1 / s2;
    gw[row * 4 + 2] = w2 / s2;
    gw[row * 4 + 3] = w3 / s2;
  }
}

// ---------------- weighted mix + RMS norm -> bf16 [2048][1024] ----------------
__global__ __launch_bounds__(256) void mix_kernel(
    const float* __restrict__ fs, const float* __restrict__ fl,
    const float* __restrict__ dlt, const float* __restrict__ v,
    const float* __restrict__ gw, const float* __restrict__ onw, u16t* __restrict__ out) {
  int row = blockIdx.x, t = threadIdx.x;
  __shared__ float sc[4];
  i64 base = (i64)row * 256 + t;
  float4 wv = *(const float4*)(gw + row * 4);
  float o = wv.x * fs[base] + wv.y * fl[base] + wv.z * dlt[base] + wv.w * v[base];
  float vals[1] = {o * o};
  block_reduce_sum<1>(vals, sc);
  float scale = rsqrtf(vals[0] * (1.0f / 256.0f) + 1e-5f);
  out[(i64)(row >> 2) * 1024 + (row & 3) * 256 + t] = f2bf(o * scale * onw[t]);
}

extern "C" void kernel_launch(void* const* d_in, const int* in_sizes, int n_in,
                              void* d_out, int out_size, void* d_ws, size_t ws_size,
                              hipStream_t stream) {
  (void)in_sizes; (void)n_in; (void)out_size; (void)ws_size;
  const float* x    = (const float*)d_in[0];
  const float* Wq   = (const float*)d_in[1];
  const float* Wk   = (const float*)d_in[2];
  const float* Wv   = (const float*)d_in[3];
  const float* Wb   = (const float*)d_in[4];
  const float* qcw  = (const float*)d_in[5];
  const float* kcw  = (const float*)d_in[6];
  const float* vcw  = (const float*)d_in[7];
  const float* gW1  = (const float*)d_in[8];
  const float* gb1  = (const float*)d_in[9];
  const float* gW2  = (const float*)d_in[10];
  const float* gb2  = (const float*)d_in[11];
  const float* temp = (const float*)d_in[12];
  const float* epsf = (const float*)d_in[13];
  const float* onw  = (const float*)d_in[14];
  const float* Wo   = (const float*)d_in[15];
  const float* firs = (const float*)d_in[16];
  const float* firl = (const float*)d_in[17];
  float* out = (float*)d_out;

  float* ws = (float*)d_ws;
  // ---- workspace map (float offsets) ----
  float* qkv_pre  = ws + 0;                       // 2048*3072 fp32
  float* branchW  = ws + 0;                       // 8192*512 fp32 (step 9+)
  float* hbase    = ws + 4194304;                 // 2048*512 fp32
  u16t*  brcat    = (u16t*)(ws + 6291456);        // 8192*1024 bf16 (own region)
  float* qbuf     = ws + 10485760; float* qn = qbuf;
  float* kbuf     = ws + 12582912; float* kn = kbuf;
  float* vbuf     = ws + 14680064;
  float* vb       = ws + 16777216;                // dead after phaseA
  u16t*  omix_bf  = (u16t*)(ws + 16777216);       // 2048*1024 bf16 (step 10+)
  u16t*  W1hT     = (u16t*)(ws + 17825792);       // 512*1024 bf16 (step 9+)
  u16t*  W1bT     = (u16t*)(ws + 18087936);       // 512*1024 bf16
  u16t*  WoT      = (u16t*)(ws + 18350080);       // 1024*1024 bf16
  float* kb       = ws + 18874368;                // dead after phaseA
  float* dlt      = ws + 18874368;                // scan output (step 6+)
  float* u_g      = ws + 20971520;                // phaseA -> scan
  u16t*  w_bf     = (u16t*)(ws + 23068672);       // negated w bf16
  u16t*  qn_bf    = (u16t*)(ws + 24117248);
  u16t*  knT      = (u16t*)(ws + 25165824);
  u16t*  attn_bf  = (u16t*)(ws + 26214400);
  float* fs       = ws + 26345472;
  float* fl       = ws + 28442624;
  u16t*  xbf      = (u16t*)(ws + 30539776);
  u16t*  WqkvT    = (u16t*)(ws + 31588352);       // 3072*1024 bf16
  float* betab    = ws + 33161216;
  float* stat     = ws + 33169408;
  float* wsum     = ws + 33267712;                // 12*512 fp32
  float* gw       = ws + 33273856;

  // 1) casts + QKV weight transposes
  castbf_kernel<<<2048, 256, 0, stream>>>(x, xbf, 524288);
  transcast_kernel<<<dim3(32, 32), 256, 0, stream>>>(Wq, 1024, 0, WqkvT, 1024);
  transcast_kernel<<<dim3(32, 32), 256, 0, stream>>>(Wk, 1024, 0, WqkvT + 1024 * 1024, 1024);
  transcast_kernel<<<dim3(32, 32), 256, 0, stream>>>(Wv, 1024, 0, WqkvT + 2048 * 1024, 1024);
  // 2) QKV GEMM
  gemm_bt_kernel<<<dim3(24, 16), 256, 0, stream>>>(xbf, WqkvT, qkv_pre, 1024, 3072);
  // 3) fused conv+silu (v also -> brcat col 768)
  conv_silu3_kernel<<<24576, 256, 0, stream>>>(qkv_pre, qcw, kcw, vcw, qbuf, kbuf, vbuf, brcat);
  // 4) beta + preprocess (emits qn_bf)
  beta_kernel<<<2048, 256, 0, stream>>>(x, Wb, betab);
  preprocess_kernel<<<8192, 256, 0, stream>>>(qbuf, kbuf, vbuf, betab, qn, kn, vb, kb, qn_bf);
  // 5) phase A (fp32 substitution; emits u fp32, w/attn/knT bf16)
  phaseA_kernel<<<256, 256, 0, stream>>>(qn, kn, vb, kb, u_g, w_bf, attn_bf, knT);
  // 6) fused delta scan (emits dlt fp32 + brcat col 512)
  delta_scan_kernel<<<128, 256, 0, stream>>>(w_bf, knT, u_g, qn_bf, attn_bf, dlt, brcat);
  // 7) fused FIR (emits fs/fl fp32 + brcat cols 0/256)
  fir2_kernel<<<512, 256, 0, stream>>>(vbuf, firs, firl, fs, fl, brcat);
  // 8) stats + wsum
  stats_kernel<<<8192, 256, 0, stream>>>(fs, fl, dlt, vbuf, stat);
  hipMemsetAsync(wsum, 0, 12 * 512 * sizeof(float), stream);
  wsum_kernel<<<96, 256, 0, stream>>>(gW1, wsum);
  // 9) gate GEMMs
  transcast_kernel<<<dim3(16, 32), 256, 0, stream>>>(gW1, 512, 0, W1hT, 1024);
  transcast_kernel<<<dim3(16, 32), 256, 0, stream>>>(gW1 + (i64)4096 * 512, 512, 0, W1bT, 1024);
  gemm_bt_kernel<<<dim3(4, 16), 256, 0, stream>>>(xbf, W1hT, hbase, 1024, 512);
  gemm_bt_kernel<<<dim3(4, 64), 256, 0, stream>>>(brcat, W1bT, branchW, 1024, 512);
  // 10) gate tail + mix (mix emits bf16 directly)
  gate_kernel<<<8192, 256, 0, stream>>>(hbase, branchW, stat, wsum, gb1, gW2, gb2, temp, epsf, gw);
  mix_kernel<<<8192, 256, 0, stream>>>(fs, fl, dlt, vbuf, gw, onw, omix_bf);
  // 11) final projection
  transcast_kernel<<<dim3(32, 32), 256, 0, stream>>>(Wo, 1024, 0, WoT, 1024);
  gemm_bt_kernel<<<dim3(8, 16), 256, 0, stream>>>(omix_bf, WoT, out, 1024, 1024);
}

// Round 9
// 374.830 us; speedup vs baseline: 4.1580x; 1.1489x over previous
//
#include <hip/hip_runtime.h>
#include <math.h>

// Problem constants
#define BB 2
#define LL 1024
#define HIDD 1024
#define NH 4
#define DD 256
#define NCH 32
#define ROWS 2048
#define HROWS 8192

typedef long long i64;
typedef unsigned short u16t;
typedef unsigned int u32t;
typedef __attribute__((ext_vector_type(8))) short short8;
typedef __attribute__((ext_vector_type(4))) float f32x4;
#define MFMA_BF16(a, b, c) __builtin_amdgcn_mfma_f32_16x16x32_bf16(a, b, c, 0, 0, 0)

__device__ __forceinline__ float sigmoidf_(float x) { return 1.0f / (1.0f + expf(-x)); }

__device__ __forceinline__ u16t f2bf(float f) {
  u32t u = __float_as_uint(f);
  u = u + 0x7FFFu + ((u >> 16) & 1u);
  return (u16t)(u >> 16);
}
__device__ __forceinline__ u32t pk2(u16t a, u16t b) { return (u32t)a | ((u32t)b << 16); }

// ---------------- block reduction helper (blockDim == 256) ----------------
template<int N>
__device__ __forceinline__ void block_reduce_sum(float* v, float* scratch) {
  int lane = threadIdx.x & 63, wid = threadIdx.x >> 6;
#pragma unroll
  for (int i = 0; i < N; i++) {
    float x = v[i];
#pragma unroll
    for (int off = 1; off < 64; off <<= 1) x += __shfl_xor(x, off);
    if (lane == 0) scratch[wid * N + i] = x;
  }
  __syncthreads();
#pragma unroll
  for (int i = 0; i < N; i++)
    v[i] = scratch[i] + scratch[N + i] + scratch[2 * N + i] + scratch[3 * N + i];
  __syncthreads();
}

// ---------------- transpose+cast body: fp32 [K][N] -> bf16 [N][K], one 32x32 tile ----------------
__device__ __forceinline__ void transcast_body(
    const float* __restrict__ in, int ldin, u16t* __restrict__ out, int ldout,
    int nbi, int kbi, float (*tile)[33]) {
  int tx = threadIdx.x & 31, ty = threadIdx.x >> 5;
  int nb = nbi * 32, kb = kbi * 32;
#pragma unroll
  for (int r = 0; r < 4; r++)
    tile[ty + r * 8][tx] = in[(i64)(kb + ty + r * 8) * ldin + nb + tx];
  __syncthreads();
#pragma unroll
  for (int r = 0; r < 4; r++)
    out[(i64)(nb + ty + r * 8) * ldout + kb + tx] = f2bf(tile[tx][ty + r * 8]);
}

// ---------------- prep (step 1): ONLY WqkvT + xbf.  W1hT/W1bT/WoT live inside
// vb's region [17825792,18874368) and must NOT be written until vb dies after
// phaseA (r7/r8 NaN bug: prep wrote them at step 1, preprocess clobbered with
// fp32 vb bytes -> NaN bf16 patterns in gate GEMM operands). ----------------
__global__ __launch_bounds__(256) void prep_kernel(
    const float* __restrict__ Wq, const float* __restrict__ Wk, const float* __restrict__ Wv,
    const float* __restrict__ x,
    u16t* __restrict__ WqkvT, u16t* __restrict__ xbf) {
  __shared__ float tile[32][33];
  int blk = blockIdx.x, t = threadIdx.x;
  if (blk < 3072) {
    int m = blk >> 10, bi = blk & 1023;
    const float* in = m == 0 ? Wq : m == 1 ? Wk : Wv;
    transcast_body(in, 1024, WqkvT + (i64)m * 1024 * 1024, 1024, bi & 31, bi >> 5, tile);
  } else {
    i64 e = ((i64)(blk - 3072) * 256 + t) * 4;
    float4 v = *(const float4*)(x + e);
    uint2 o;
    o.x = pk2(f2bf(v.x), f2bf(v.y));
    o.y = pk2(f2bf(v.z), f2bf(v.w));
    *(uint2*)(xbf + e) = o;
  }
}

// ---------------- prep2 (after phaseA, vb dead): W1hT + W1bT + WoT ----------------
__global__ __launch_bounds__(256) void prep2_kernel(
    const float* __restrict__ gW1, const float* __restrict__ Wo,
    u16t* __restrict__ W1hT, u16t* __restrict__ W1bT, u16t* __restrict__ WoT) {
  __shared__ float tile[32][33];
  int blk = blockIdx.x;
  if (blk < 1024) {
    int which = blk >> 9, bi = blk & 511;
    const float* in = gW1 + (which ? (i64)4096 * 512 : 0);
    transcast_body(in, 512, which ? W1bT : W1hT, 1024, bi & 15, bi >> 4, tile);
  } else {
    int bi = blk - 1024;
    transcast_body(Wo, 1024, WoT, 1024, bi & 31, bi >> 5, tile);
  }
}

// ---------------- bf16 MFMA GEMM body: A[M][K], B[N][K] -> C[M][N] fp32 ----------------
__device__ __forceinline__ void gemm_bt_body(
    const u16t* __restrict__ A, const u16t* __restrict__ B,
    float* __restrict__ C, int K, int ldc, int n0, int m0,
    u16t* As, u16t* Bs) {
  int t = threadIdx.x;
  int w = t >> 6, lane = t & 63;
  int l15 = lane & 15, quad = lane >> 4;
  int wm = (w & 1) * 64, wn = (w >> 1) * 64;
  f32x4 acc[4][4] = {};
  int srow = t >> 1, shalf = (t & 1) * 16;
  const u16t* Ag = A + (i64)(m0 + srow) * K + shalf;
  const u16t* Bg = B + (i64)(n0 + srow) * K + shalf;
  for (int k0 = 0; k0 < K; k0 += 32) {
    *(uint4*)&As[srow * 40 + shalf] = *(const uint4*)(Ag + k0);
    *(uint4*)&As[srow * 40 + shalf + 8] = *(const uint4*)(Ag + k0 + 8);
    *(uint4*)&Bs[srow * 40 + shalf] = *(const uint4*)(Bg + k0);
    *(uint4*)&Bs[srow * 40 + shalf + 8] = *(const uint4*)(Bg + k0 + 8);
    __syncthreads();
    short8 a[4], b[4];
#pragma unroll
    for (int mt = 0; mt < 4; mt++)
      a[mt] = *(const short8*)&As[(wm + mt * 16 + l15) * 40 + quad * 8];
#pragma unroll
    for (int nt = 0; nt < 4; nt++)
      b[nt] = *(const short8*)&Bs[(wn + nt * 16 + l15) * 40 + quad * 8];
#pragma unroll
    for (int mt = 0; mt < 4; mt++)
#pragma unroll
      for (int nt = 0; nt < 4; nt++)
        acc[mt][nt] = MFMA_BF16(a[mt], b[nt], acc[mt][nt]);
    __syncthreads();
  }
#pragma unroll
  for (int mt = 0; mt < 4; mt++) {
    int r0 = m0 + wm + mt * 16 + quad * 4;
#pragma unroll
    for (int nt = 0; nt < 4; nt++) {
      int cc = n0 + wn + nt * 16 + l15;
#pragma unroll
      for (int rg = 0; rg < 4; rg++)
        C[(i64)(r0 + rg) * ldc + cc] = acc[mt][nt][rg];
    }
  }
}

__global__ __launch_bounds__(256) void gemm_bt_kernel(
    const u16t* __restrict__ A, const u16t* __restrict__ B,
    float* __restrict__ C, int K, int ldc) {
  __shared__ u16t As[128 * 40];
  __shared__ u16t Bs[128 * 40];
  gemm_bt_body(A, B, C, K, ldc, blockIdx.x * 128, blockIdx.y * 128, As, Bs);
}

// ---------------- fused causal depthwise conv (K=4) + silu for q,k,v ----------------
__global__ __launch_bounds__(256) void conv_silu3_kernel(
    const float* __restrict__ pre, const float* __restrict__ qw,
    const float* __restrict__ kw, const float* __restrict__ vw,
    float* __restrict__ qo, float* __restrict__ ko, float* __restrict__ vo,
    u16t* __restrict__ brcat) {
  int seg = blockIdx.x >> 13;
  int idx = (blockIdx.x & 8191) * 256 + threadIdx.x;
  int c = idx & 1023, row = idx >> 10, l = row & 1023;
  const float* w = seg == 0 ? qw : seg == 1 ? kw : vw;
  float* out = seg == 0 ? qo : seg == 1 ? ko : vo;
  float4 wv = *(const float4*)(w + c * 4);
  const float* base = pre + (i64)row * 3072 + (seg << 10) + c;
  float acc = wv.w * base[0];
  if (l >= 1) acc += wv.z * base[-3072];
  if (l >= 2) acc += wv.y * base[-2 * 3072];
  if (l >= 3) acc += wv.x * base[-3 * 3072];
  float r = acc * sigmoidf_(acc);
  out[(i64)row * 1024 + c] = r;
  if (seg == 2)
    brcat[((i64)row * 4 + (c >> 8)) * 1024 + 768 + (c & 255)] = f2bf(r);
}

// ---------------- beta = sigmoid(x @ Wb) ----------------
__global__ __launch_bounds__(256) void beta_kernel(
    const float* __restrict__ x, const float* __restrict__ Wb, float* __restrict__ beta) {
  int row = blockIdx.x, t = threadIdx.x;
  __shared__ float sc[16];
  float a[4] = {0, 0, 0, 0};
  for (int c = t; c < 1024; c += 256) {
    float xv = x[(i64)row * 1024 + c];
    float4 wv = *(const float4*)(Wb + c * 4);
    a[0] += xv * wv.x; a[1] += xv * wv.y; a[2] += xv * wv.z; a[3] += xv * wv.w;
  }
  block_reduce_sum<4>(a, sc);
  if (t == 0) {
#pragma unroll
    for (int g = 0; g < 4; g++) beta[row * 4 + g] = sigmoidf_(a[g]);
  }
}

// ---------------- l2norm(q,k), v*beta, kn*beta; qn bf16 in delta layout ----------------
__global__ __launch_bounds__(256) void preprocess_kernel(
    const float* __restrict__ q, const float* __restrict__ k, const float* __restrict__ v,
    const float* __restrict__ beta, float* __restrict__ qn, float* __restrict__ kn,
    float* __restrict__ vb, float* __restrict__ kb, u16t* __restrict__ qnbf) {
  int row = blockIdx.x, t = threadIdx.x;   // row = (b*1024+l)*4+h
  __shared__ float sc[8];
  i64 base = (i64)row * 256 + t;
  float qv = q[base], kv = k[base], vv = v[base];
  float vals[2] = {qv * qv, kv * kv};
  block_reduce_sum<2>(vals, sc);
  float qi = rsqrtf(vals[0] + 1e-6f), ki = rsqrtf(vals[1] + 1e-6f);
  float bet = beta[row];
  float qnv = qv * qi, knv = kv * ki;
  qn[base] = qnv;
  kn[base] = knv;
  vb[base] = vv * bet;
  kb[base] = knv * bet;
  int b = row >> 12, l = (row >> 2) & 1023, h = row & 3;
  qnbf[((i64)(b * 4 + h) * 1024 + l) * 256 + t] = f2bf(qnv);
}

// ---------------- phase A: per-chunk UT-transform ----------------
__global__ __launch_bounds__(256) void phaseA_kernel(
    const float* __restrict__ qn, const float* __restrict__ kn,
    const float* __restrict__ vb, const float* __restrict__ kb,
    float* __restrict__ u_g, u16t* __restrict__ w_bf, u16t* __restrict__ attn_bf,
    u16t* __restrict__ knT) {
  __shared__ float KN[32][260];
  __shared__ float Ms[32][32];
  int blk = blockIdx.x, t = threadIdx.x;
  int i = blk & 31, bh = blk >> 5;
  int rbase = ((bh >> 2) * LL + i * 32) * NH + (bh & 3);
  i64 bhn = blk;
#pragma unroll
  for (int ii = 0; ii < 8; ii++) {
    int fid = t + ii * 256;
    int c = fid >> 6, dq = (fid & 63) << 2;
    *(float4*)&KN[c][dq] = *(const float4*)(kn + (i64)(rbase + c * NH) * 256 + dq);
  }
  __syncthreads();
  int c = t >> 3, e0 = (t & 7) * 4;
  const float* kbp = kb + (i64)(rbase + c * NH) * 256;
  const float* qp = qn + (i64)(rbase + c * NH) * 256;
  float am[4] = {0, 0, 0, 0}, aa[4] = {0, 0, 0, 0};
  for (int d = 0; d < 256; d += 4) {
    float4 kv = *(const float4*)(kbp + d);
    float4 qv = *(const float4*)(qp + d);
#pragma unroll
    for (int z = 0; z < 4; z++) {
      float4 nv = *(const float4*)&KN[e0 + z][d];
      am[z] += kv.x * nv.x + kv.y * nv.y + kv.z * nv.z + kv.w * nv.w;
      aa[z] += qv.x * nv.x + qv.y * nv.y + qv.z * nv.z + qv.w * nv.w;
    }
  }
  {
    uint2 o;
    u16t a0 = (e0 + 0 <= c) ? f2bf(aa[0]) : 0;
    u16t a1 = (e0 + 1 <= c) ? f2bf(aa[1]) : 0;
    u16t a2 = (e0 + 2 <= c) ? f2bf(aa[2]) : 0;
    u16t a3 = (e0 + 3 <= c) ? f2bf(aa[3]) : 0;
    o.x = pk2(a0, a1); o.y = pk2(a2, a3);
    *(uint2*)(attn_bf + bhn * 1024 + c * 32 + e0) = o;
  }
#pragma unroll
  for (int z = 0; z < 4; z++) {
    int e = e0 + z;
    Ms[c][e] = (e < c) ? am[z] : 0.0f;
  }
  __syncthreads();
  float uc[32], wc[32];
#pragma unroll
  for (int cc = 0; cc < 32; cc++) {
    float uval = vb[(i64)(rbase + cc * NH) * 256 + t];
    float wval = kb[(i64)(rbase + cc * NH) * 256 + t];
#pragma unroll
    for (int c2 = 0; c2 < cc; c2++) {
      float m = Ms[cc][c2];
      uval -= m * uc[c2];
      wval -= m * wc[c2];
    }
    uc[cc] = uval; wc[cc] = wval;
    u_g[(bhn * 32 + cc) * 256 + t] = uval;
    w_bf[(bhn * 32 + cc) * 256 + t] = f2bf(-wval);
  }
  int d = t;
  u16t o[32];
#pragma unroll
  for (int cc = 0; cc < 32; cc++) o[cc] = f2bf(KN[cc][d]);
#pragma unroll
  for (int z = 0; z < 4; z++) {
    uint4 vv;
    vv.x = pk2(o[z * 8 + 0], o[z * 8 + 1]);
    vv.y = pk2(o[z * 8 + 2], o[z * 8 + 3]);
    vv.z = pk2(o[z * 8 + 4], o[z * 8 + 5]);
    vv.w = pk2(o[z * 8 + 6], o[z * 8 + 7]);
    *(uint4*)(knT + (bhn * 256 + d) * 32 + z * 8) = vv;
  }
}

// ---------------- delta scan body (round-6 verbatim semantics) ----------------
#define SROW 264
struct ScanBuf {
  short8 m8[8];
  f32x4 uc4;
  short8 af;
  short8 kf[4];
};

__device__ void delta_scan_body(
    int blk,
    const u16t* __restrict__ wbf, const u16t* __restrict__ knT,
    const float* __restrict__ u_g, const u16t* __restrict__ qnbf,
    const u16t* __restrict__ attnbf,
    float* __restrict__ dlt, u16t* __restrict__ brcat,
    u16t* Sbf, u16t* Ubf) {
  int t = threadIdx.x, w = t >> 6, lane = t & 63;
  int l15 = lane & 15, quad = lane >> 4;
  int bh = blk & 7, jb = blk >> 3, j0 = jb * 16;
  int b_ = bh >> 2, h_ = bh & 3;
  bool isU = (w < 2);
  int wc = isU ? w : (w - 2);
  for (int idx = t; idx < 16 * SROW; idx += 256) Sbf[idx] = 0;
  f32x4 accS[4] = {};
  __syncthreads();

  auto load_chunk = [&](int i, ScanBuf& B) {
    i64 bhn = (i64)bh * 32 + i;
    const u16t* mbase = isU
        ? wbf + (bhn * 32 + wc * 16 + l15) * 256 + quad * 8
        : qnbf + ((i64)bh * 1024 + i * 32 + wc * 16 + l15) * 256 + quad * 8;
#pragma unroll
    for (int kd = 0; kd < 8; kd++) B.m8[kd] = *(const short8*)(mbase + kd * 32);
    if (isU) {
      int cm = wc * 16 + quad * 4;
#pragma unroll
      for (int r = 0; r < 4; r++)
        B.uc4[r] = u_g[(bhn * 32 + cm + r) * 256 + j0 + l15];
    } else {
      B.af = *(const short8*)(attnbf + bhn * 1024 + (wc * 16 + l15) * 32 + quad * 8);
    }
#pragma unroll
    for (int dt = 0; dt < 4; dt++)
      B.kf[dt] = *(const short8*)(knT + (bhn * 256 + w * 64 + dt * 16 + l15) * 32 + quad * 8);
  };

  auto process = [&](int i, ScanBuf& B) {
    f32x4 zero = {};
    f32x4 ca = isU ? B.uc4 : zero;
    f32x4 cb = zero;
#pragma unroll
    for (int kd = 0; kd < 4; kd++) {
      short8 sfa = *(const short8*)&Sbf[l15 * SROW + kd * 32 + quad * 8];
      short8 sfb = *(const short8*)&Sbf[l15 * SROW + (kd + 4) * 32 + quad * 8];
      ca = MFMA_BF16(B.m8[kd], sfa, ca);
      cb = MFMA_BF16(B.m8[kd + 4], sfb, cb);
    }
    f32x4 cacc;
#pragma unroll
    for (int r = 0; r < 4; r++) cacc[r] = ca[r] + cb[r];
    if (isU) {
      int cm = wc * 16 + quad * 4;
      uint2 o;
      o.x = pk2(f2bf(cacc[0]), f2bf(cacc[1]));
      o.y = pk2(f2bf(cacc[2]), f2bf(cacc[3]));
      *(uint2*)&Ubf[l15 * 40 + cm] = o;
    }
    __syncthreads();
    short8 bu = *(const short8*)&Ubf[l15 * 40 + quad * 8];
    if (!isU) {
      cacc = MFMA_BF16(B.af, bu, cacc);
#pragma unroll
      for (int rg = 0; rg < 4; rg++) {
        int l = i * 32 + wc * 16 + quad * 4 + rg;
        i64 row = ((i64)b_ * 1024 + l) * 4 + h_;
        dlt[row * 256 + j0 + l15] = cacc[rg];
        brcat[row * 1024 + 512 + j0 + l15] = f2bf(cacc[rg]);
      }
    }
#pragma unroll
    for (int dt = 0; dt < 4; dt++) accS[dt] = MFMA_BF16(B.kf[dt], bu, accS[dt]);
#pragma unroll
    for (int dt = 0; dt < 4; dt++) {
      uint2 o;
      o.x = pk2(f2bf(accS[dt][0]), f2bf(accS[dt][1]));
      o.y = pk2(f2bf(accS[dt][2]), f2bf(accS[dt][3]));
      *(uint2*)&Sbf[l15 * SROW + w * 64 + dt * 16 + quad * 4] = o;
    }
    __syncthreads();
  };

  ScanBuf b0, b1;
  load_chunk(0, b0);
#pragma unroll 1
  for (int ii = 0; ii < 16; ii++) {
    int i = ii * 2;
    load_chunk(i + 1, b1);
    process(i, b0);
    if (ii < 15) load_chunk(i + 2, b0);
    process(i + 1, b1);
  }
}

// ---------------- FIR body ----------------
__device__ void fir2_body(
    int blk, const float* __restrict__ v,
    const float* __restrict__ f_s, const float* __restrict__ f_l,
    float* __restrict__ fs, float* __restrict__ fl, u16t* __restrict__ brcat) {
  int t = threadIdx.x;
  int b = blk >> 8, h = (blk >> 6) & 3, lc = blk & 63;
  int l0 = lc * 16;
  float flw[31], fsw[3];
  const float* flp = f_l + ((i64)h * 256 + t) * 31;
#pragma unroll
  for (int j = 0; j < 31; j++) flw[j] = flp[j];
  const float* fsp = f_s + ((i64)h * 256 + t) * 3;
#pragma unroll
  for (int j = 0; j < 3; j++) fsw[j] = fsp[j];
  float win[46];
#pragma unroll
  for (int r = 0; r < 46; r++) {
    int l = l0 - 30 + r;
    win[r] = (l >= 0) ? v[(((i64)b * 1024 + l) * 4 + h) * 256 + t] : 0.0f;
  }
#pragma unroll
  for (int i = 0; i < 16; i++) {
    float al = 0.0f;
#pragma unroll
    for (int j = 0; j < 31; j++) al += flw[j] * win[i + j];
    float as = fsw[0] * win[i + 28] + fsw[1] * win[i + 29] + fsw[2] * win[i + 30];
    i64 row = ((i64)b * 1024 + (l0 + i)) * 4 + h;
    fs[row * 256 + t] = as;
    fl[row * 256 + t] = al;
    brcat[row * 1024 + t] = f2bf(as);
    brcat[row * 1024 + 256 + t] = f2bf(al);
  }
}

// ---------------- mega: scan(128) + fir(512) + hbase gemm(64) + wsum(24) ----------------
__global__ __launch_bounds__(256) void mega_kernel(
    const u16t* __restrict__ wbf, const u16t* __restrict__ knT,
    const float* __restrict__ u_g, const u16t* __restrict__ qnbf,
    const u16t* __restrict__ attnbf, float* __restrict__ dlt, u16t* __restrict__ brcat,
    const float* __restrict__ vbuf, const float* __restrict__ firs,
    const float* __restrict__ firl, float* __restrict__ fs, float* __restrict__ fl,
    const u16t* __restrict__ xbf, const u16t* __restrict__ W1hT, float* __restrict__ hbase,
    const float* __restrict__ gW1, float* __restrict__ wsum) {
  __shared__ __attribute__((aligned(16))) char smem[20480];
  int blk = blockIdx.x;
  if (blk < 128) {
    u16t* Sbf = (u16t*)smem;
    u16t* Ubf = Sbf + 16 * SROW;
    delta_scan_body(blk, wbf, knT, u_g, qnbf, attnbf, dlt, brcat, Sbf, Ubf);
  } else if (blk < 640) {
    fir2_body(blk - 128, vbuf, firs, firl, fs, fl, brcat);
  } else if (blk < 704) {
    int bi = blk - 640;
    u16t* As = (u16t*)smem;
    u16t* Bs = As + 128 * 40;
    gemm_bt_body(xbf, W1hT, hbase, 1024, 512, (bi & 3) * 128, (bi >> 2) * 128, As, Bs);
  } else {
    int bi = blk - 704;          // 24 blocks: 12 stats x 2 col-halves
    int s12 = bi >> 1, col = (bi & 1) * 256 + threadIdx.x;
    const float* p = gW1 + (i64)(1024 + s12 * 256) * 512 + col;
    float acc = 0.0f;
    for (int r = 0; r < 256; r++) acc += p[(i64)r * 512];
    wsum[s12 * 512 + col] = acc;
  }
}

// ---------------- stats body ----------------
__device__ void stats_body(
    int row, const float* __restrict__ fs, const float* __restrict__ fl,
    const float* __restrict__ dlt, const float* __restrict__ v,
    float* __restrict__ stat, float* sc, float* scm) {
  int t = threadIdx.x;
  const float* brs[4] = {fs, fl, dlt, v};
#pragma unroll
  for (int p = 0; p < 4; p++) {
    float x = brs[p][(i64)row * 256 + t];
    float vals[2] = {x, x * x};
    block_reduce_sum<2>(vals, sc);
    float m = x;
#pragma unroll
    for (int off = 1; off < 64; off <<= 1) m = fmaxf(m, __shfl_xor(m, off));
    int lane = t & 63, wid = t >> 6;
    if (lane == 0) scm[wid] = m;
    __syncthreads();
    if (t == 0) {
      float mx = fmaxf(fmaxf(scm[0], scm[1]), fmaxf(scm[2], scm[3]));
      stat[row * 12 + p * 3 + 0] = vals[0] * (1.0f / 256.0f);
      stat[row * 12 + p * 3 + 1] = sqrtf(fmaxf(vals[1] * (1.0f / 256.0f), 1e-8f));
      stat[row * 12 + p * 3 + 2] = mx;
    }
    __syncthreads();
  }
}

// ---------------- sb: branchW gemm(256) + stats(8192) ----------------
__global__ __launch_bounds__(256) void sb_kernel(
    const u16t* __restrict__ brcat, const u16t* __restrict__ W1bT,
    float* __restrict__ branchW,
    const float* __restrict__ fs, const float* __restrict__ fl,
    const float* __restrict__ dlt, const float* __restrict__ vbuf,
    float* __restrict__ stat) {
  __shared__ __attribute__((aligned(16))) char smem[20480];
  int blk = blockIdx.x;
  if (blk < 256) {
    u16t* As = (u16t*)smem;
    u16t* Bs = As + 128 * 40;
    gemm_bt_body(brcat, W1bT, branchW, 1024, 512, (blk & 3) * 128, (blk >> 2) * 128, As, Bs);
  } else {
    float* sc = (float*)smem;
    float* scm = sc + 8;
    stats_body(blk - 256, fs, fl, dlt, vbuf, stat, sc, scm);
  }
}

// ---------------- fused gate MLP tail + mix + RMS norm ----------------
__global__ __launch_bounds__(256) void gatemix_kernel(
    const float* __restrict__ hbase, const float* __restrict__ brW,
    const float* __restrict__ stat, const float* __restrict__ wsum,
    const float* __restrict__ gb1, const float* __restrict__ gW2,
    const float* __restrict__ gb2, const float* __restrict__ temp,
    const float* __restrict__ epsf,
    const float* __restrict__ fs, const float* __restrict__ fl,
    const float* __restrict__ dlt, const float* __restrict__ v,
    const float* __restrict__ onw, u16t* __restrict__ out) {
  int row = blockIdx.x, t = threadIdx.x;
  int bl = row >> 2, h = row & 3;
  __shared__ float sc[16];
  __shared__ float gwsh[4];
  float st[12];
#pragma unroll
  for (int s = 0; s < 12; s++) st[s] = stat[row * 12 + s];
  float lg[4] = {0, 0, 0, 0};
#pragma unroll
  for (int jj = 0; jj < 2; jj++) {
    int o = jj * 256 + t;
    float hm = hbase[(i64)bl * 512 + o] + brW[(i64)row * 512 + o] + gb1[o];
#pragma unroll
    for (int s = 0; s < 12; s++) hm += st[s] * wsum[s * 512 + o];
    float ge = 0.5f * hm * (1.0f + erff(hm * 0.70710678118654752f));
    float4 w2 = *(const float4*)(gW2 + o * 4);
    lg[0] += ge * w2.x; lg[1] += ge * w2.y; lg[2] += ge * w2.z; lg[3] += ge * w2.w;
  }
  block_reduce_sum<4>(lg, sc);
  if (t == 0) {
    float tt = fminf(fmaxf(temp[h], 0.2f), 10.0f);
    float l0 = (lg[0] + gb2[0]) / tt;
    float l1 = (lg[1] + gb2[1]) / tt;
    float l2 = (lg[2] + gb2[2]) / tt;
    float l3 = (lg[3] + gb2[3]) / tt;
    float m = fmaxf(fmaxf(l0, l1), fmaxf(l2, l3));
    float e0 = expf(l0 - m), e1 = expf(l1 - m), e2 = expf(l2 - m), e3 = expf(l3 - m);
    float ssum = e0 + e1 + e2 + e3;
    float w0 = e0 / ssum, w1 = e1 / ssum, w2 = e2 / ssum, w3 = e3 / ssum;
    w0 = fmaxf(w0, fminf(fmaxf(epsf[h * 4 + 0], 1e-7f), 0.1f));
    w1 = fmaxf(w1, fminf(fmaxf(epsf[h * 4 + 1], 1e-7f), 0.1f));
    w2 = fmaxf(w2, fminf(fmaxf(epsf[h * 4 + 2], 1e-7f), 0.1f));
    w3 = fmaxf(w3, fminf(fmaxf(epsf[h * 4 + 3], 1e-7f), 0.1f));
    float s2 = w0 + w1 + w2 + w3;
    gwsh[0] = w0 / s2; gwsh[1] = w1 / s2; gwsh[2] = w2 / s2; gwsh[3] = w3 / s2;
  }
  __syncthreads();
  float g0 = gwsh[0], g1 = gwsh[1], g2 = gwsh[2], g3 = gwsh[3];
  i64 base = (i64)row * 256 + t;
  float o = g0 * fs[base] + g1 * fl[base] + g2 * dlt[base] + g3 * v[base];
  float vals[1] = {o * o};
  block_reduce_sum<1>(vals, sc);
  float scale = rsqrtf(vals[0] * (1.0f / 256.0f) + 1e-5f);
  out[(i64)bl * 1024 + h * 256 + t] = f2bf(o * scale * onw[t]);
}

extern "C" void kernel_launch(void* const* d_in, const int* in_sizes, int n_in,
                              void* d_out, int out_size, void* d_ws, size_t ws_size,
                              hipStream_t stream) {
  (void)in_sizes; (void)n_in; (void)out_size; (void)ws_size;
  const float* x    = (const float*)d_in[0];
  const float* Wq   = (const float*)d_in[1];
  const float* Wk   = (const float*)d_in[2];
  const float* Wv   = (const float*)d_in[3];
  const float* Wb   = (const float*)d_in[4];
  const float* qcw  = (const float*)d_in[5];
  const float* kcw  = (const float*)d_in[6];
  const float* vcw  = (const float*)d_in[7];
  const float* gW1  = (const float*)d_in[8];
  const float* gb1  = (const float*)d_in[9];
  const float* gW2  = (const float*)d_in[10];
  const float* gb2  = (const float*)d_in[11];
  const float* temp = (const float*)d_in[12];
  const float* epsf = (const float*)d_in[13];
  const float* onw  = (const float*)d_in[14];
  const float* Wo   = (const float*)d_in[15];
  const float* firs = (const float*)d_in[16];
  const float* firl = (const float*)d_in[17];
  float* out = (float*)d_out;

  float* ws = (float*)d_ws;
  // ---- workspace map (float offsets); W1hT/W1bT/WoT share vb's region and
  // are only written AFTER phaseA (prep2) — r7/r8 NaN bug fix ----
  float* qkv_pre  = ws + 0;                       // 2048*3072 fp32 (dead after conv)
  float* branchW  = ws + 0;                       // 8192*512 fp32 (sb+)
  float* hbase    = ws + 4194304;                 // 2048*512 fp32 (mega+)
  u16t*  brcat    = (u16t*)(ws + 6291456);        // 8192*1024 bf16
  float* qbuf     = ws + 10485760; float* qn = qbuf;
  float* kbuf     = ws + 12582912; float* kn = kbuf;
  float* vbuf     = ws + 14680064;
  float* vb       = ws + 16777216;                // dead after phaseA
  u16t*  omix_bf  = (u16t*)(ws + 16777216);       // gatemix+
  u16t*  W1hT     = (u16t*)(ws + 17825792);       // prep2+ (inside dead vb)
  u16t*  W1bT     = (u16t*)(ws + 18087936);
  u16t*  WoT      = (u16t*)(ws + 18350080);
  float* kb       = ws + 18874368;                // dead after phaseA
  float* dlt      = ws + 18874368;                // scan output
  float* u_g      = ws + 20971520;
  u16t*  w_bf     = (u16t*)(ws + 23068672);
  u16t*  qn_bf    = (u16t*)(ws + 24117248);
  u16t*  knT      = (u16t*)(ws + 25165824);
  u16t*  attn_bf  = (u16t*)(ws + 26214400);
  float* fs       = ws + 26345472;
  float* fl       = ws + 28442624;
  u16t*  xbf      = (u16t*)(ws + 30539776);
  u16t*  WqkvT    = (u16t*)(ws + 31588352);
  float* betab    = ws + 33161216;                // 8192 fp32
  float* stat     = ws + 33169408;
  float* wsum     = ws + 33267712;

  // 1) prep: QKV weight transpose + x cast (W1/Wo transposes deferred to prep2)
  prep_kernel<<<5120, 256, 0, stream>>>(Wq, Wk, Wv, x, WqkvT, xbf);
  // 2) QKV GEMM
  gemm_bt_kernel<<<dim3(24, 16), 256, 0, stream>>>(xbf, WqkvT, qkv_pre, 1024, 3072);
  // 3) conv+silu (v also -> brcat col 768)
  conv_silu3_kernel<<<24576, 256, 0, stream>>>(qkv_pre, qcw, kcw, vcw, qbuf, kbuf, vbuf, brcat);
  // 4) beta + preprocess (emits qn_bf; writes vb over W1hT/W1bT/WoT slots — they're not live yet)
  beta_kernel<<<2048, 256, 0, stream>>>(x, Wb, betab);
  preprocess_kernel<<<8192, 256, 0, stream>>>(qbuf, kbuf, vbuf, betab, qn, kn, vb, kb, qn_bf);
  // 5) phase A (last reader of vb/kb)
  phaseA_kernel<<<256, 256, 0, stream>>>(qn, kn, vb, kb, u_g, w_bf, attn_bf, knT);
  // 5.5) prep2: W1hT/W1bT/WoT transposes into the now-dead vb region
  prep2_kernel<<<2048, 256, 0, stream>>>(gW1, Wo, W1hT, W1bT, WoT);
  // 6) mega: delta scan + FIR + hbase GEMM + wsum (co-scheduled)
  mega_kernel<<<728, 256, 0, stream>>>(w_bf, knT, u_g, qn_bf, attn_bf, dlt, brcat,
                                       vbuf, firs, firl, fs, fl,
                                       xbf, W1hT, hbase, gW1, wsum);
  // 7) branchW GEMM + stats (co-scheduled)
  sb_kernel<<<8448, 256, 0, stream>>>(brcat, W1bT, branchW, fs, fl, dlt, vbuf, stat);
  // 8) gate tail + mix + RMS (emits omix_bf)
  gatemix_kernel<<<8192, 256, 0, stream>>>(hbase, branchW, stat, wsum, gb1, gW2, gb2,
                                           temp, epsf, fs, fl, dlt, vbuf, onw, omix_bf);
  // 9) final projection
  gemm_bt_kernel<<<dim3(8, 16), 256, 0, stream>>>(omix_bf, WoT, out, 1024, 1024);
}